// Round 11
// baseline (1121.752 us; speedup 1.0000x reference)
//
#include <hip/hip_runtime.h>
#include <math.h>

#define NN 50000
#define NF 63
#define NE 800000
#define NL 10000
#define NB 4
#define NLAY 5
#define BN (NB*NN)                 // 200000 rows
#define NTILES (BN/64)             // 3125 blocks (64 rows = 16 nodes each)
#define SCAN_NBLK ((NN+255)/256)   // 196

using f32x4  = __attribute__((ext_vector_type(4))) float;
using bf16x8 = __attribute__((ext_vector_type(8))) __bf16;

__device__ __forceinline__ float frcp(float x){ return __builtin_amdgcn_rcpf(x); }
__device__ __forceinline__ float sigm(float v){ return frcp(1.f + __expf(-v)); }
__device__ __forceinline__ float tanh_f(float v){ return fmaf(-2.f, frcp(__expf(2.f*v) + 1.f), 1.f); }

__device__ __forceinline__ ushort f2bf(float f){
    uint u = __builtin_bit_cast(uint, f);
    u += 0x7fffu + ((u >> 16) & 1u);
    return (ushort)(u >> 16);
}
__device__ __forceinline__ float bf_lo(uint v){ return __builtin_bit_cast(float, v << 16); }
__device__ __forceinline__ float bf_hi(uint v){ return __builtin_bit_cast(float, v & 0xffff0000u); }
__device__ __forceinline__ float bfu(ushort v){ return __builtin_bit_cast(float, ((uint)v) << 16); }

__device__ __forceinline__ bf16x8 ldfrag(const ushort* p){
    uint4 v = *(const uint4*)p;
    return __builtin_bit_cast(bf16x8, v);
}
__device__ __forceinline__ f32x4 MFMA(bf16x8 a, bf16x8 b, f32x4 c){
    return __builtin_amdgcn_mfma_f32_16x16x32_bf16(a, b, c, 0, 0, 0);
}

// ---------------- CSR build ----------------
__global__ void k_hist(const int* __restrict__ edges, int* __restrict__ cnt){
    int e = blockIdx.x*256 + threadIdx.x;
    if (e < NE) atomicAdd(&cnt[edges[NE + e]], 1);
}

__global__ void k_scan1(const int* __restrict__ cnt, int* __restrict__ tmp, int* __restrict__ bsum){
    __shared__ int sh[256];
    int tx = threadIdx.x, i = blockIdx.x*256 + tx;
    int v = (i < NN) ? cnt[i] : 0;
    sh[tx] = v; __syncthreads();
    for (int off = 1; off < 256; off <<= 1){
        int u = (tx >= off) ? sh[tx-off] : 0;
        __syncthreads();
        sh[tx] += u;
        __syncthreads();
    }
    int incl = sh[tx];
    if (i < NN) tmp[i] = incl - v;
    if (tx == 255) bsum[blockIdx.x] = incl;
}

__global__ void k_scan2(const int* __restrict__ bsum, int* __restrict__ boff){
    __shared__ int sh[256];
    int tx = threadIdx.x;
    int v = (tx < SCAN_NBLK) ? bsum[tx] : 0;
    sh[tx] = v; __syncthreads();
    for (int off = 1; off < 256; off <<= 1){
        int u = (tx >= off) ? sh[tx-off] : 0;
        __syncthreads();
        sh[tx] += u;
        __syncthreads();
    }
    boff[tx] = sh[tx] - v;
}

__global__ void k_scan3(const int* __restrict__ tmp, const int* __restrict__ boff,
                        int* __restrict__ row_start, int* __restrict__ cursor){
    int i = blockIdx.x*256 + threadIdx.x;
    if (i < NN){
        int rs = tmp[i] + boff[blockIdx.x];
        row_start[i] = rs;
        cursor[i] = rs;
    }
    if (i == 0) row_start[NN] = NE;
}

__global__ void k_fillcsr(const int* __restrict__ edges, int* __restrict__ cursor, int* __restrict__ csr_src){
    int e = blockIdx.x*256 + threadIdx.x;
    if (e < NE){
        int d = edges[NE + e];
        int pos = atomicAdd(&cursor[d], 1);
        csr_src[pos] = edges[e];
    }
}

// ---------------- weight prep ----------------
// wfb[i][n][k] = sum_c ggc[i][k][c] * wih[n][c]
__global__ void k_prep(const float* __restrict__ wih, const float* __restrict__ whh,
                       const float* __restrict__ aiw, const float* __restrict__ ajw,
                       const float* __restrict__ ggc,
                       ushort* __restrict__ whhb, ushort* __restrict__ aiwb,
                       ushort* __restrict__ ajwb, ushort* __restrict__ wfb){
    int i = blockIdx.x*256 + threadIdx.x;       // 0..106495
    if (i < 12288)        whhb[i]        = f2bf(whh[i]);
    else if (i < 28672)   aiwb[i-12288]  = f2bf(aiw[i-12288]);
    else if (i < 45056)   ajwb[i-28672]  = f2bf(ajw[i-28672]);
    else {
        int t = i - 45056;                       // 0..61439
        int lay = t / 12288;
        int rem = t % 12288;
        int n = rem >> 6, k = rem & 63;
        const float* W  = ggc + lay*4096 + k*64;
        const float* wr = wih + n*64;
        float s = 0.f;
        #pragma unroll 8
        for (int c = 0; c < 64; ++c) s = fmaf(W[c], wr[c], s);
        wfb[t] = f2bf(s);
    }
}

// ---------------- x0 build (bf16 interleaved records [n][b][64]) ----------------
__global__ void k_x0(const float* __restrict__ nodes, ushort* __restrict__ x0I){
    int f = blockIdx.x*256 + threadIdx.x;       // 8B group index, BN*16 total
    int row = f >> 4, c4 = f & 15;
    int n = row % NN, b = row / NN;
    float v[4];
    #pragma unroll
    for (int i = 0; i < 4; ++i){
        int c = c4*4 + i;
        v[i] = (c < NF) ? nodes[(size_t)n*NF + c] : 0.f;
    }
    uint2 pk;
    pk.x = (uint)f2bf(v[0]) | ((uint)f2bf(v[1]) << 16);
    pk.y = (uint)f2bf(v[2]) | ((uint)f2bf(v[3]) << 16);
    *(uint2*)(x0I + ((size_t)n*4 + b)*64 + c4*4) = pk;
}

__global__ void k_cov(const float* __restrict__ cov, const int* __restrict__ c2l,
                      ushort* __restrict__ x0I){
    int i = blockIdx.x*256 + threadIdx.x;
    if (i < NB*NL){
        int b = i / NL, j = i % NL;
        int nd = c2l[j];
        x0I[((size_t)nd*4 + b)*64 + 63] = f2bf(cov[i]);
    }
}

// ---------------- slice-partitioned agg: XCD-local L2 working set ----------------
// Record = 512B = 8 slices x 64B. slice = blockIdx & 7 -> with round-robin block->XCD
// dispatch, each XCD only touches one slice of every record (3.2 MB, L2-resident).
// Wave = one dst; 4 subgroups of 16 lanes each take a different edge; 2x unroll.
__global__ __launch_bounds__(256) void k_aggS(const ushort* __restrict__ xI,
                                              const int* __restrict__ row_start,
                                              const int* __restrict__ csr_src,
                                              ushort* __restrict__ aggx){
    int tx = threadIdx.x, l = tx & 63, w = tx >> 6;
    int slice = blockIdx.x & 7;
    int d = __builtin_amdgcn_readfirstlane(((int)blockIdx.x >> 3)*4 + w);
    int eo = l >> 4;                            // edge offset within 4-edge step
    int t  = l & 15;                            // uint lane within 64B slice
    const uint off = (uint)(slice*32 + t*2);    // ushort offset in record
    int e0 = row_start[d], e1 = row_start[d+1];
    float a0 = 0.f, a1 = 0.f;
    int e = e0 + eo;
    for (; e + 4 < e1; e += 8){                 // 8 edges in flight across wave
        int s0 = csr_src[e], s1 = csr_src[e+4];
        uint v0 = *(const uint*)(xI + (size_t)s0*256 + off);
        uint v1 = *(const uint*)(xI + (size_t)s1*256 + off);
        a0 += bf_lo(v0) + bf_lo(v1);
        a1 += bf_hi(v0) + bf_hi(v1);
    }
    if (e < e1){
        int s0 = csr_src[e];
        uint v0 = *(const uint*)(xI + (size_t)s0*256 + off);
        a0 += bf_lo(v0); a1 += bf_hi(v0);
    }
    a0 += __shfl_xor(a0, 16); a0 += __shfl_xor(a0, 32);
    a1 += __shfl_xor(a1, 16); a1 += __shfl_xor(a1, 32);
    if (eo == 0){
        uint o = (uint)f2bf(a0) | ((uint)f2bf(a1) << 16);
        *(uint*)(aggx + (size_t)d*256 + off) = o;
    }
}

// ---------------- shared GRU core: staged LDS tiles -> xnew ----------------
__device__ __forceinline__ void gru_core(const ushort* sAgg, const ushort* sX,
                                         const ushort* __restrict__ wfb, const ushort* __restrict__ whhb,
                                         const float* __restrict__ bih, const float* __restrict__ bhh,
                                         int li, int q, int n0, ushort xn[4][4]){
    f32x4 Cr[4], Cz[4], Cxn[4], Chn[4];
    #pragma unroll
    for (int m = 0; m < 4; ++m){
        Cr[m]=(f32x4){0.f,0.f,0.f,0.f}; Cz[m]=(f32x4){0.f,0.f,0.f,0.f};
        Cxn[m]=(f32x4){0.f,0.f,0.f,0.f}; Chn[m]=(f32x4){0.f,0.f,0.f,0.f};
    }
    #pragma unroll
    for (int ks = 0; ks < 4; ++ks){
        const ushort* wb = (ks < 2) ? wfb : whhb;
        const ushort* sT = (ks < 2) ? sAgg : sX;
        const int kb = (ks & 1)*32;
        bf16x8 Br = ldfrag(wb + (size_t)(n0 + li)*64 + kb + q*8);
        bf16x8 Bz = ldfrag(wb + (size_t)(64 + n0 + li)*64 + kb + q*8);
        bf16x8 Bn = ldfrag(wb + (size_t)(128 + n0 + li)*64 + kb + q*8);
        #pragma unroll
        for (int m = 0; m < 4; ++m){
            bf16x8 A = ldfrag(&sT[(m*16 + li)*72 + kb + q*8]);
            Cr[m] = MFMA(A, Br, Cr[m]);
            Cz[m] = MFMA(A, Bz, Cz[m]);
            if (ks < 2) Cxn[m] = MFMA(A, Bn, Cxn[m]);
            else        Chn[m] = MFMA(A, Bn, Chn[m]);
        }
    }
    const int c = n0 + li;
    const float br_ = bih[c]     + bhh[c];
    const float bz_ = bih[64+c]  + bhh[64+c];
    const float bn_ = bih[128+c];
    const float bh_ = bhh[128+c];
    #pragma unroll
    for (int m = 0; m < 4; ++m){
        #pragma unroll
        for (int rg = 0; rg < 4; ++rg){
            int rl = m*16 + q*4 + rg;
            float r = sigm(Cr[m][rg] + br_);
            float z = sigm(Cz[m][rg] + bz_);
            float nng = tanh_f(Cxn[m][rg] + bn_ + r*(Chn[m][rg] + bh_));
            float v = (1.f - z)*nng + z*bfu(sX[rl*72 + c]);
            xn[m][rg] = f2bf(v);
        }
    }
}

// ---------------- GRU layer (non-last): staged, 1 barrier, in-place ----------------
__global__ __launch_bounds__(256) void k_gruF(const ushort* __restrict__ xsrc,
                                              const ushort* __restrict__ aggx,
                                              const ushort* __restrict__ wfb, const ushort* __restrict__ whhb,
                                              const float* __restrict__ bih, const float* __restrict__ bhh,
                                              ushort* __restrict__ xout){
    __shared__ __align__(16) ushort sAgg[64*72];
    __shared__ __align__(16) ushort sX[64*72];
    const int tx = threadIdx.x;
    const int l  = tx & 63, li = l & 15, q = l >> 4;
    const int w  = __builtin_amdgcn_readfirstlane(tx >> 6);
    const int R0 = blockIdx.x*64;

    #pragma unroll
    for (int it = 0; it < 2; ++it){
        int idx = it*256 + tx, r = idx >> 3, g = idx & 7;
        size_t go = (size_t)(R0 + r)*64 + g*8;
        *(uint4*)(&sAgg[r*72 + g*8]) = *(const uint4*)(aggx + go);
        *(uint4*)(&sX[r*72 + g*8])   = *(const uint4*)(xsrc + go);
    }
    __syncthreads();

    ushort xn[4][4];
    gru_core(sAgg, sX, wfb, whhb, bih, bhh, li, q, 16*w, xn);

    const int c = 16*w + li;
    #pragma unroll
    for (int m = 0; m < 4; ++m)
        #pragma unroll
        for (int rg = 0; rg < 4; ++rg)
            xout[(size_t)(R0 + m*16 + q*4 + rg)*64 + c] = xn[m][rg];
}

// ---------------- GRU layer (last): + fused attention ----------------
__global__ __launch_bounds__(256) void k_gruL(const ushort* __restrict__ xsrc,
                                              const ushort* __restrict__ aggx,
                                              const ushort* __restrict__ wfb, const ushort* __restrict__ whhb,
                                              const float* __restrict__ bih, const float* __restrict__ bhh,
                                              const ushort* __restrict__ x0I,
                                              const ushort* __restrict__ aiwb, const float* __restrict__ aib,
                                              const ushort* __restrict__ ajwb, const float* __restrict__ ajb,
                                              float* __restrict__ pooled16){
    __shared__ __align__(16) ushort sAgg[64*72];
    __shared__ __align__(16) ushort sX[64*72];
    const int tx = threadIdx.x;
    const int l  = tx & 63, li = l & 15, q = l >> 4;
    const int w  = __builtin_amdgcn_readfirstlane(tx >> 6);
    const int R0 = blockIdx.x*64;

    #pragma unroll
    for (int it = 0; it < 2; ++it){
        int idx = it*256 + tx, r = idx >> 3, g = idx & 7;
        size_t go = (size_t)(R0 + r)*64 + g*8;
        *(uint4*)(&sAgg[r*72 + g*8]) = *(const uint4*)(aggx + go);
        *(uint4*)(&sX[r*72 + g*8])   = *(const uint4*)(xsrc + go);
    }
    __syncthreads();

    ushort xn[4][4];
    gru_core(sAgg, sX, wfb, whhb, bih, bhh, li, q, 16*w, xn);
    __syncthreads();                              // all reads of sAgg/sX done

    // cat tile: x' -> sAgg (transpose from C-layout), x0 -> sX (coalesced)
    const int c = 16*w + li;
    #pragma unroll
    for (int m = 0; m < 4; ++m)
        #pragma unroll
        for (int rg = 0; rg < 4; ++rg)
            sAgg[(m*16 + q*4 + rg)*72 + c] = xn[m][rg];
    #pragma unroll
    for (int it = 0; it < 2; ++it){
        int idx = it*256 + tx, r = idx >> 3, g = idx & 7;
        *(uint4*)(&sX[r*72 + g*8]) = *(const uint4*)(x0I + (size_t)(R0 + r)*64 + g*8);
    }
    __syncthreads();

    f32x4 Ai[2][4], Aj[2][4];
    #pragma unroll
    for (int t = 0; t < 2; ++t)
        #pragma unroll
        for (int m = 0; m < 4; ++m){ Ai[t][m]=(f32x4){0.f,0.f,0.f,0.f}; Aj[t][m]=(f32x4){0.f,0.f,0.f,0.f}; }

    const int nb0 = 32*w;
    #pragma unroll
    for (int ks = 0; ks < 4; ++ks){
        const ushort* sT = (ks < 2) ? sAgg : sX;
        const int kb = (ks & 1)*32;
        bf16x8 Bi[2], Bj[2];
        #pragma unroll
        for (int t = 0; t < 2; ++t){
            Bi[t] = ldfrag(aiwb + (size_t)(nb0 + 16*t + li)*128 + ks*32 + q*8);
            Bj[t] = ldfrag(ajwb + (size_t)(nb0 + 16*t + li)*128 + ks*32 + q*8);
        }
        #pragma unroll
        for (int m = 0; m < 4; ++m){
            bf16x8 A = ldfrag(&sT[(m*16 + li)*72 + kb + q*8]);
            #pragma unroll
            for (int t = 0; t < 2; ++t){
                Ai[t][m] = MFMA(A, Bi[t], Ai[t][m]);
                Aj[t][m] = MFMA(A, Bj[t], Aj[t][m]);
            }
        }
    }

    float* pb = pooled16 + (size_t)(blockIdx.x & 15)*512;
    #pragma unroll
    for (int t = 0; t < 2; ++t){
        int cc = nb0 + 16*t + li;
        float bia = aib[cc], bja = ajb[cc];
        float vs[4] = {0.f, 0.f, 0.f, 0.f};
        #pragma unroll
        for (int m = 0; m < 4; ++m){
            #pragma unroll
            for (int rg = 0; rg < 4; ++rg){
                float s = sigm(Ai[t][m][rg] + bia);
                float a = Aj[t][m][rg] + bja;
                a = a > 0.f ? a : 0.f;
                vs[rg] += s*a;                    // batch == rg (interleaved rows)
            }
        }
        #pragma unroll
        for (int b = 0; b < 4; ++b){
            vs[b] += __shfl_xor(vs[b], 16);
            vs[b] += __shfl_xor(vs[b], 32);
        }
        if (l < 16){
            #pragma unroll
            for (int b = 0; b < 4; ++b) atomicAdd(&pb[b*128 + nb0 + 16*t + l], vs[b]);
        }
    }
}

// ---------------- final MLP + critic ----------------
__global__ void k_final(const float* __restrict__ pooled16, const float* __restrict__ mw,
                        const float* __restrict__ mb, const float* __restrict__ cw,
                        const float* __restrict__ cb, float* __restrict__ out){
    __shared__ float red[256];
    int t = threadIdx.x;
    for (int b = 0; b < NB; ++b){
        float acc = mb[t];
        #pragma unroll 4
        for (int k = 0; k < 128; ++k){
            float p = 0.f;
            #pragma unroll
            for (int kb = 0; kb < 16; ++kb) p += pooled16[kb*512 + b*128 + k];
            p = p > 0.f ? p : 0.f;
            acc = fmaf(p, mw[t*128 + k], acc);
        }
        float st = acc > 0.f ? acc : 0.f;
        red[t] = st * cw[t];
        __syncthreads();
        for (int off = 128; off > 0; off >>= 1){
            if (t < off) red[t] += red[t + off];
            __syncthreads();
        }
        if (t == 0) out[b] = red[0] + cb[0];
        __syncthreads();
    }
}

extern "C" void kernel_launch(void* const* d_in, const int* in_sizes, int n_in,
                              void* d_out, int out_size, void* d_ws, size_t ws_size,
                              hipStream_t stream) {
    const float* cov   = (const float*)d_in[0];
    const float* nodes = (const float*)d_in[1];
    const int*   edges = (const int*)d_in[2];
    const int*   c2l   = (const int*)d_in[3];
    const float* ggc   = (const float*)d_in[4];
    const float* wih   = (const float*)d_in[5];
    const float* whh   = (const float*)d_in[6];
    const float* bih   = (const float*)d_in[7];
    const float* bhh   = (const float*)d_in[8];
    const float* aiw   = (const float*)d_in[9];
    const float* aib   = (const float*)d_in[10];
    const float* ajw   = (const float*)d_in[11];
    const float* ajb   = (const float*)d_in[12];
    const float* mlpw  = (const float*)d_in[13];
    const float* mlpb  = (const float*)d_in[14];
    const float* cw    = (const float*)d_in[15];
    const float* cb    = (const float*)d_in[16];
    float* out = (float*)d_out;

    const size_t XSZ = (size_t)BN * 64;          // 12.8M elements
    float* ws = (float*)d_ws;
    float* pooled16 = ws;                        // 16*512 floats
    ushort* xS    = (ushort*)(pooled16 + 8192);  // bf16 interleaved state (in-place)
    ushort* x0I   = xS + XSZ;                    // bf16 interleaved x0
    ushort* aggx  = x0I + XSZ;                   // bf16 agg, interleaved records
    ushort* whhb  = aggx + XSZ;                  // 12288
    ushort* aiwb  = whhb + 12288;                // 16384
    ushort* ajwb  = aiwb + 16384;                // 16384
    ushort* wfb   = ajwb + 16384;                // 5*12288 fused ih weights
    int* cnt       = (int*)(wfb + 61440);
    int* tmp       = cnt + NN;
    int* bsum      = tmp + NN;
    int* boff      = bsum + 256;
    int* row_start = boff + 256;
    int* cursor    = row_start + (NN + 1);
    int* csr_src   = cursor + NN;

    hipMemsetAsync(cnt, 0, (size_t)NN*sizeof(int), stream);
    hipMemsetAsync(pooled16, 0, 8192*sizeof(float), stream);

    k_prep<<<416, 256, 0, stream>>>(wih, whh, aiw, ajw, ggc, whhb, aiwb, ajwb, wfb);

    k_hist<<<(NE + 255)/256, 256, 0, stream>>>(edges, cnt);
    k_scan1<<<SCAN_NBLK, 256, 0, stream>>>(cnt, tmp, bsum);
    k_scan2<<<1, 256, 0, stream>>>(bsum, boff);
    k_scan3<<<SCAN_NBLK, 256, 0, stream>>>(tmp, boff, row_start, cursor);
    k_fillcsr<<<(NE + 255)/256, 256, 0, stream>>>(edges, cursor, csr_src);

    k_x0<<<(BN*16)/256, 256, 0, stream>>>(nodes, x0I);
    k_cov<<<(NB*NL + 255)/256, 256, 0, stream>>>(cov, c2l, x0I);

    for (int i = 0; i < NLAY; ++i){
        const ushort* xin = (i == 0) ? x0I : xS;
        const ushort* wf  = wfb + (size_t)i*12288;
        k_aggS<<<(NN/4)*8, 256, 0, stream>>>(xin, row_start, csr_src, aggx);
        if (i < NLAY - 1)
            k_gruF<<<NTILES, 256, 0, stream>>>(xin, aggx, wf, whhb, bih, bhh, xS);
        else
            k_gruL<<<NTILES, 256, 0, stream>>>(xin, aggx, wf, whhb, bih, bhh,
                                               x0I, aiwb, aib, ajwb, ajb, pooled16);
    }

    k_final<<<1, 256, 0, stream>>>(pooled16, mlpw, mlpb, cw, cb, out);
    (void)in_sizes; (void)n_in; (void)out_size; (void)ws_size;
}

// Round 12
// 691.819 us; speedup vs baseline: 1.6215x; 1.6215x over previous
//
#include <hip/hip_runtime.h>
#include <math.h>

#define NN 50000
#define NF 63
#define NE 800000
#define NL 10000
#define NB 4
#define NLAY 5
#define BN (NB*NN)                 // 200000 rows
#define NTILES (BN/64)             // 3125 blocks (64 rows = 16 nodes each)
#define SCAN_NBLK ((NN+255)/256)   // 196

using f32x4  = __attribute__((ext_vector_type(4))) float;
using bf16x8 = __attribute__((ext_vector_type(8))) __bf16;

__device__ __forceinline__ float frcp(float x){ return __builtin_amdgcn_rcpf(x); }
__device__ __forceinline__ float sigm(float v){ return frcp(1.f + __expf(-v)); }
__device__ __forceinline__ float tanh_f(float v){ return fmaf(-2.f, frcp(__expf(2.f*v) + 1.f), 1.f); }

__device__ __forceinline__ ushort f2bf(float f){
    uint u = __builtin_bit_cast(uint, f);
    u += 0x7fffu + ((u >> 16) & 1u);
    return (ushort)(u >> 16);
}
__device__ __forceinline__ float bf_lo(uint v){ return __builtin_bit_cast(float, v << 16); }
__device__ __forceinline__ float bf_hi(uint v){ return __builtin_bit_cast(float, v & 0xffff0000u); }
__device__ __forceinline__ float bfu(ushort v){ return __builtin_bit_cast(float, ((uint)v) << 16); }

__device__ __forceinline__ bf16x8 ldfrag(const ushort* p){
    uint4 v = *(const uint4*)p;
    return __builtin_bit_cast(bf16x8, v);
}
__device__ __forceinline__ f32x4 MFMA(bf16x8 a, bf16x8 b, f32x4 c){
    return __builtin_amdgcn_mfma_f32_16x16x32_bf16(a, b, c, 0, 0, 0);
}

// ---------------- CSR build ----------------
__global__ void k_hist(const int* __restrict__ edges, int* __restrict__ cnt){
    int e = blockIdx.x*256 + threadIdx.x;
    if (e < NE) atomicAdd(&cnt[edges[NE + e]], 1);
}

__global__ void k_scan1(const int* __restrict__ cnt, int* __restrict__ tmp, int* __restrict__ bsum){
    __shared__ int sh[256];
    int tx = threadIdx.x, i = blockIdx.x*256 + tx;
    int v = (i < NN) ? cnt[i] : 0;
    sh[tx] = v; __syncthreads();
    for (int off = 1; off < 256; off <<= 1){
        int u = (tx >= off) ? sh[tx-off] : 0;
        __syncthreads();
        sh[tx] += u;
        __syncthreads();
    }
    int incl = sh[tx];
    if (i < NN) tmp[i] = incl - v;
    if (tx == 255) bsum[blockIdx.x] = incl;
}

__global__ void k_scan2(const int* __restrict__ bsum, int* __restrict__ boff){
    __shared__ int sh[256];
    int tx = threadIdx.x;
    int v = (tx < SCAN_NBLK) ? bsum[tx] : 0;
    sh[tx] = v; __syncthreads();
    for (int off = 1; off < 256; off <<= 1){
        int u = (tx >= off) ? sh[tx-off] : 0;
        __syncthreads();
        sh[tx] += u;
        __syncthreads();
    }
    boff[tx] = sh[tx] - v;
}

__global__ void k_scan3(const int* __restrict__ tmp, const int* __restrict__ boff,
                        int* __restrict__ row_start, int* __restrict__ cursor){
    int i = blockIdx.x*256 + threadIdx.x;
    if (i < NN){
        int rs = tmp[i] + boff[blockIdx.x];
        row_start[i] = rs;
        cursor[i] = rs;
    }
    if (i == 0) row_start[NN] = NE;
}

__global__ void k_fillcsr(const int* __restrict__ edges, int* __restrict__ cursor, int* __restrict__ csr_src){
    int e = blockIdx.x*256 + threadIdx.x;
    if (e < NE){
        int d = edges[NE + e];
        int pos = atomicAdd(&cursor[d], 1);
        csr_src[pos] = edges[e];
    }
}

// ---------------- weight prep ----------------
// wfb[i][n][k] = sum_c ggc[i][k][c] * wih[n][c]
__global__ void k_prep(const float* __restrict__ wih, const float* __restrict__ whh,
                       const float* __restrict__ aiw, const float* __restrict__ ajw,
                       const float* __restrict__ ggc,
                       ushort* __restrict__ whhb, ushort* __restrict__ aiwb,
                       ushort* __restrict__ ajwb, ushort* __restrict__ wfb){
    int i = blockIdx.x*256 + threadIdx.x;       // 0..106495
    if (i < 12288)        whhb[i]        = f2bf(whh[i]);
    else if (i < 28672)   aiwb[i-12288]  = f2bf(aiw[i-12288]);
    else if (i < 45056)   ajwb[i-28672]  = f2bf(ajw[i-28672]);
    else {
        int t = i - 45056;                       // 0..61439
        int lay = t / 12288;
        int rem = t % 12288;
        int n = rem >> 6, k = rem & 63;
        const float* W  = ggc + lay*4096 + k*64;
        const float* wr = wih + n*64;
        float s = 0.f;
        #pragma unroll 8
        for (int c = 0; c < 64; ++c) s = fmaf(W[c], wr[c], s);
        wfb[t] = f2bf(s);
    }
}

// ---------------- x0 build: interleaved x0I + batch-invariant x0C ----------------
__global__ void k_x0(const float* __restrict__ nodes, ushort* __restrict__ x0I,
                     ushort* __restrict__ x0C){
    int f = blockIdx.x*256 + threadIdx.x;       // 8B group index, BN*16 total
    int row = f >> 4, c4 = f & 15;
    int n = row % NN, b = row / NN;
    float v[4];
    #pragma unroll
    for (int i = 0; i < 4; ++i){
        int c = c4*4 + i;
        v[i] = (c < NF) ? nodes[(size_t)n*NF + c] : 0.f;
    }
    uint2 pk;
    pk.x = (uint)f2bf(v[0]) | ((uint)f2bf(v[1]) << 16);
    pk.y = (uint)f2bf(v[2]) | ((uint)f2bf(v[3]) << 16);
    *(uint2*)(x0I + ((size_t)n*4 + b)*64 + c4*4) = pk;
    if (b == 0) *(uint2*)(x0C + (size_t)n*64 + c4*4) = pk;   // col63 stays 0
}

__global__ void k_cov(const float* __restrict__ cov, const int* __restrict__ c2l,
                      ushort* __restrict__ x0I, ushort* __restrict__ covB){
    int i = blockIdx.x*256 + threadIdx.x;
    if (i < NB*NL){
        int b = i / NL, j = i % NL;
        int nd = c2l[j];
        ushort vb = f2bf(cov[i]);
        x0I[((size_t)nd*4 + b)*64 + 63] = vb;
        covB[(size_t)nd*4 + b] = vb;
    }
}

// ---------------- layer-0 agg: batch-invariant gather (128B + 8B per edge) ----------------
__global__ __launch_bounds__(256) void k_agg0(const ushort* __restrict__ x0C,
                                              const ushort* __restrict__ covB,
                                              const int* __restrict__ row_start,
                                              const int* __restrict__ csr_src,
                                              ushort* __restrict__ aggx){
    int tx = threadIdx.x, l = tx & 63, w = tx >> 6;
    int d = __builtin_amdgcn_readfirstlane(blockIdx.x*4 + w);
    int h = l >> 5, t = l & 31;                 // half-wave per edge; lane t covers cols 2t,2t+1
    int e0 = row_start[d], e1 = row_start[d+1];
    float a0 = 0.f, a1 = 0.f, c = 0.f;
    int e = e0 + h;
    for (; e + 6 < e1; e += 8){
        int s0 = csr_src[e], s1 = csr_src[e+2], s2 = csr_src[e+4], s3 = csr_src[e+6];
        uint v0 = *(const uint*)(x0C + (size_t)s0*64 + t*2);
        uint v1 = *(const uint*)(x0C + (size_t)s1*64 + t*2);
        uint v2 = *(const uint*)(x0C + (size_t)s2*64 + t*2);
        uint v3 = *(const uint*)(x0C + (size_t)s3*64 + t*2);
        a0 += bf_lo(v0)+bf_lo(v1)+bf_lo(v2)+bf_lo(v3);
        a1 += bf_hi(v0)+bf_hi(v1)+bf_hi(v2)+bf_hi(v3);
        if (t < 4){
            c += bf_lo((uint)covB[(size_t)s0*4 + t]) + bf_lo((uint)covB[(size_t)s1*4 + t])
               + bf_lo((uint)covB[(size_t)s2*4 + t]) + bf_lo((uint)covB[(size_t)s3*4 + t]);
        }
    }
    for (; e < e1; e += 2){
        int s0 = csr_src[e];
        uint v0 = *(const uint*)(x0C + (size_t)s0*64 + t*2);
        a0 += bf_lo(v0); a1 += bf_hi(v0);
        if (t < 4) c += bf_lo((uint)covB[(size_t)s0*4 + t]);
    }
    a0 += __shfl_xor(a0, 32);
    a1 += __shfl_xor(a1, 32);
    c  += __shfl_xor(c, 32);
    float cb0 = __shfl(c, 0), cb1 = __shfl(c, 1), cb2 = __shfl(c, 2), cb3 = __shfl(c, 3);
    if (h == 0){
        uint pk = (uint)f2bf(a0) | ((uint)f2bf(a1) << 16);
        float cb[4] = {cb0, cb1, cb2, cb3};
        #pragma unroll
        for (int b = 0; b < 4; ++b){
            uint o = pk;
            if (t == 31) o = (o & 0xffffu) | ((uint)f2bf(cb[b]) << 16);
            *(uint*)(aggx + (size_t)d*256 + b*64 + t*2) = o;   // interleaved record
        }
    }
}

// ---------------- generic agg: half-wave per edge, uint4 loads, 8 edges in flight ----------------
__global__ __launch_bounds__(256) void k_agg(const ushort* __restrict__ xI,
                                             const int* __restrict__ row_start,
                                             const int* __restrict__ csr_src,
                                             ushort* __restrict__ aggx){
    int tx = threadIdx.x, l = tx & 63, w = tx >> 6;
    int d = __builtin_amdgcn_readfirstlane(blockIdx.x*4 + w);
    int h = l >> 5;                     // half-wave: even/odd edges
    int t = l & 31;                     // 16B group within the 512B record
    const uint off = (uint)(t*8);       // ushort offset
    int e0 = row_start[d], e1 = row_start[d+1];
    float a0=0.f,a1=0.f,a2=0.f,a3=0.f,a4=0.f,a5=0.f,a6=0.f,a7=0.f;
    int e = e0 + h;
    for (; e + 6 < e1; e += 8){         // 4 pair-loads = 8 edges in flight
        int s0 = csr_src[e], s1 = csr_src[e+2], s2 = csr_src[e+4], s3 = csr_src[e+6];
        uint4 v0 = *(const uint4*)(xI + (size_t)s0*256 + off);
        uint4 v1 = *(const uint4*)(xI + (size_t)s1*256 + off);
        uint4 v2 = *(const uint4*)(xI + (size_t)s2*256 + off);
        uint4 v3 = *(const uint4*)(xI + (size_t)s3*256 + off);
        a0 += bf_lo(v0.x)+bf_lo(v1.x)+bf_lo(v2.x)+bf_lo(v3.x);
        a1 += bf_hi(v0.x)+bf_hi(v1.x)+bf_hi(v2.x)+bf_hi(v3.x);
        a2 += bf_lo(v0.y)+bf_lo(v1.y)+bf_lo(v2.y)+bf_lo(v3.y);
        a3 += bf_hi(v0.y)+bf_hi(v1.y)+bf_hi(v2.y)+bf_hi(v3.y);
        a4 += bf_lo(v0.z)+bf_lo(v1.z)+bf_lo(v2.z)+bf_lo(v3.z);
        a5 += bf_hi(v0.z)+bf_hi(v1.z)+bf_hi(v2.z)+bf_hi(v3.z);
        a6 += bf_lo(v0.w)+bf_lo(v1.w)+bf_lo(v2.w)+bf_lo(v3.w);
        a7 += bf_hi(v0.w)+bf_hi(v1.w)+bf_hi(v2.w)+bf_hi(v3.w);
    }
    for (; e < e1; e += 2){
        int s0 = csr_src[e];
        uint4 v0 = *(const uint4*)(xI + (size_t)s0*256 + off);
        a0 += bf_lo(v0.x); a1 += bf_hi(v0.x);
        a2 += bf_lo(v0.y); a3 += bf_hi(v0.y);
        a4 += bf_lo(v0.z); a5 += bf_hi(v0.z);
        a6 += bf_lo(v0.w); a7 += bf_hi(v0.w);
    }
    a0 += __shfl_xor(a0, 32); a1 += __shfl_xor(a1, 32);
    a2 += __shfl_xor(a2, 32); a3 += __shfl_xor(a3, 32);
    a4 += __shfl_xor(a4, 32); a5 += __shfl_xor(a5, 32);
    a6 += __shfl_xor(a6, 32); a7 += __shfl_xor(a7, 32);
    if (h == 0){
        uint4 o;
        o.x = (uint)f2bf(a0) | ((uint)f2bf(a1) << 16);
        o.y = (uint)f2bf(a2) | ((uint)f2bf(a3) << 16);
        o.z = (uint)f2bf(a4) | ((uint)f2bf(a5) << 16);
        o.w = (uint)f2bf(a6) | ((uint)f2bf(a7) << 16);
        *(uint4*)(aggx + (size_t)d*256 + off) = o;   // 32 lanes x 16B = full record
    }
}

// ---------------- shared GRU core: staged LDS tiles -> xnew ----------------
__device__ __forceinline__ void gru_core(const ushort* sAgg, const ushort* sX,
                                         const ushort* __restrict__ wfb, const ushort* __restrict__ whhb,
                                         const float* __restrict__ bih, const float* __restrict__ bhh,
                                         int li, int q, int n0, ushort xn[4][4]){
    f32x4 Cr[4], Cz[4], Cxn[4], Chn[4];
    #pragma unroll
    for (int m = 0; m < 4; ++m){
        Cr[m]=(f32x4){0.f,0.f,0.f,0.f}; Cz[m]=(f32x4){0.f,0.f,0.f,0.f};
        Cxn[m]=(f32x4){0.f,0.f,0.f,0.f}; Chn[m]=(f32x4){0.f,0.f,0.f,0.f};
    }
    #pragma unroll
    for (int ks = 0; ks < 4; ++ks){
        const ushort* wb = (ks < 2) ? wfb : whhb;
        const ushort* sT = (ks < 2) ? sAgg : sX;
        const int kb = (ks & 1)*32;
        bf16x8 Br = ldfrag(wb + (size_t)(n0 + li)*64 + kb + q*8);
        bf16x8 Bz = ldfrag(wb + (size_t)(64 + n0 + li)*64 + kb + q*8);
        bf16x8 Bn = ldfrag(wb + (size_t)(128 + n0 + li)*64 + kb + q*8);
        #pragma unroll
        for (int m = 0; m < 4; ++m){
            bf16x8 A = ldfrag(&sT[(m*16 + li)*72 + kb + q*8]);
            Cr[m] = MFMA(A, Br, Cr[m]);
            Cz[m] = MFMA(A, Bz, Cz[m]);
            if (ks < 2) Cxn[m] = MFMA(A, Bn, Cxn[m]);
            else        Chn[m] = MFMA(A, Bn, Chn[m]);
        }
    }
    const int c = n0 + li;
    const float br_ = bih[c]     + bhh[c];
    const float bz_ = bih[64+c]  + bhh[64+c];
    const float bn_ = bih[128+c];
    const float bh_ = bhh[128+c];
    #pragma unroll
    for (int m = 0; m < 4; ++m){
        #pragma unroll
        for (int rg = 0; rg < 4; ++rg){
            int rl = m*16 + q*4 + rg;
            float r = sigm(Cr[m][rg] + br_);
            float z = sigm(Cz[m][rg] + bz_);
            float nng = tanh_f(Cxn[m][rg] + bn_ + r*(Chn[m][rg] + bh_));
            float v = (1.f - z)*nng + z*bfu(sX[rl*72 + c]);
            xn[m][rg] = f2bf(v);
        }
    }
}

// ---------------- GRU layer (non-last): staged, 1 barrier, in-place ----------------
__global__ __launch_bounds__(256) void k_gruF(const ushort* __restrict__ xsrc,
                                              const ushort* __restrict__ aggx,
                                              const ushort* __restrict__ wfb, const ushort* __restrict__ whhb,
                                              const float* __restrict__ bih, const float* __restrict__ bhh,
                                              ushort* __restrict__ xout){
    __shared__ __align__(16) ushort sAgg[64*72];
    __shared__ __align__(16) ushort sX[64*72];
    const int tx = threadIdx.x;
    const int l  = tx & 63, li = l & 15, q = l >> 4;
    const int w  = __builtin_amdgcn_readfirstlane(tx >> 6);
    const int R0 = blockIdx.x*64;

    #pragma unroll
    for (int it = 0; it < 2; ++it){
        int idx = it*256 + tx, r = idx >> 3, g = idx & 7;
        size_t go = (size_t)(R0 + r)*64 + g*8;
        *(uint4*)(&sAgg[r*72 + g*8]) = *(const uint4*)(aggx + go);
        *(uint4*)(&sX[r*72 + g*8])   = *(const uint4*)(xsrc + go);
    }
    __syncthreads();

    ushort xn[4][4];
    gru_core(sAgg, sX, wfb, whhb, bih, bhh, li, q, 16*w, xn);

    const int c = 16*w + li;
    #pragma unroll
    for (int m = 0; m < 4; ++m)
        #pragma unroll
        for (int rg = 0; rg < 4; ++rg)
            xout[(size_t)(R0 + m*16 + q*4 + rg)*64 + c] = xn[m][rg];
}

// ---------------- GRU layer (last): + fused attention ----------------
__global__ __launch_bounds__(256) void k_gruL(const ushort* __restrict__ xsrc,
                                              const ushort* __restrict__ aggx,
                                              const ushort* __restrict__ wfb, const ushort* __restrict__ whhb,
                                              const float* __restrict__ bih, const float* __restrict__ bhh,
                                              const ushort* __restrict__ x0I,
                                              const ushort* __restrict__ aiwb, const float* __restrict__ aib,
                                              const ushort* __restrict__ ajwb, const float* __restrict__ ajb,
                                              float* __restrict__ pooled16){
    __shared__ __align__(16) ushort sAgg[64*72];
    __shared__ __align__(16) ushort sX[64*72];
    const int tx = threadIdx.x;
    const int l  = tx & 63, li = l & 15, q = l >> 4;
    const int w  = __builtin_amdgcn_readfirstlane(tx >> 6);
    const int R0 = blockIdx.x*64;

    #pragma unroll
    for (int it = 0; it < 2; ++it){
        int idx = it*256 + tx, r = idx >> 3, g = idx & 7;
        size_t go = (size_t)(R0 + r)*64 + g*8;
        *(uint4*)(&sAgg[r*72 + g*8]) = *(const uint4*)(aggx + go);
        *(uint4*)(&sX[r*72 + g*8])   = *(const uint4*)(xsrc + go);
    }
    __syncthreads();

    ushort xn[4][4];
    gru_core(sAgg, sX, wfb, whhb, bih, bhh, li, q, 16*w, xn);
    __syncthreads();                              // all reads of sAgg/sX done

    // cat tile: x' -> sAgg (transpose from C-layout), x0 -> sX (coalesced)
    const int c = 16*w + li;
    #pragma unroll
    for (int m = 0; m < 4; ++m)
        #pragma unroll
        for (int rg = 0; rg < 4; ++rg)
            sAgg[(m*16 + q*4 + rg)*72 + c] = xn[m][rg];
    #pragma unroll
    for (int it = 0; it < 2; ++it){
        int idx = it*256 + tx, r = idx >> 3, g = idx & 7;
        *(uint4*)(&sX[r*72 + g*8]) = *(const uint4*)(x0I + (size_t)(R0 + r)*64 + g*8);
    }
    __syncthreads();

    f32x4 Ai[2][4], Aj[2][4];
    #pragma unroll
    for (int t = 0; t < 2; ++t)
        #pragma unroll
        for (int m = 0; m < 4; ++m){ Ai[t][m]=(f32x4){0.f,0.f,0.f,0.f}; Aj[t][m]=(f32x4){0.f,0.f,0.f,0.f}; }

    const int nb0 = 32*w;
    #pragma unroll
    for (int ks = 0; ks < 4; ++ks){
        const ushort* sT = (ks < 2) ? sAgg : sX;
        const int kb = (ks & 1)*32;
        bf16x8 Bi[2], Bj[2];
        #pragma unroll
        for (int t = 0; t < 2; ++t){
            Bi[t] = ldfrag(aiwb + (size_t)(nb0 + 16*t + li)*128 + ks*32 + q*8);
            Bj[t] = ldfrag(ajwb + (size_t)(nb0 + 16*t + li)*128 + ks*32 + q*8);
        }
        #pragma unroll
        for (int m = 0; m < 4; ++m){
            bf16x8 A = ldfrag(&sT[(m*16 + li)*72 + kb + q*8]);
            #pragma unroll
            for (int t = 0; t < 2; ++t){
                Ai[t][m] = MFMA(A, Bi[t], Ai[t][m]);
                Aj[t][m] = MFMA(A, Bj[t], Aj[t][m]);
            }
        }
    }

    float* pb = pooled16 + (size_t)(blockIdx.x & 15)*512;
    #pragma unroll
    for (int t = 0; t < 2; ++t){
        int cc = nb0 + 16*t + li;
        float bia = aib[cc], bja = ajb[cc];
        float vs[4] = {0.f, 0.f, 0.f, 0.f};
        #pragma unroll
        for (int m = 0; m < 4; ++m){
            #pragma unroll
            for (int rg = 0; rg < 4; ++rg){
                float s = sigm(Ai[t][m][rg] + bia);
                float a = Aj[t][m][rg] + bja;
                a = a > 0.f ? a : 0.f;
                vs[rg] += s*a;                    // batch == rg (interleaved rows)
            }
        }
        #pragma unroll
        for (int b = 0; b < 4; ++b){
            vs[b] += __shfl_xor(vs[b], 16);
            vs[b] += __shfl_xor(vs[b], 32);
        }
        if (l < 16){
            #pragma unroll
            for (int b = 0; b < 4; ++b) atomicAdd(&pb[b*128 + nb0 + 16*t + l], vs[b]);
        }
    }
}

// ---------------- final MLP + critic ----------------
__global__ void k_final(const float* __restrict__ pooled16, const float* __restrict__ mw,
                        const float* __restrict__ mb, const float* __restrict__ cw,
                        const float* __restrict__ cb, float* __restrict__ out){
    __shared__ float red[256];
    int t = threadIdx.x;
    for (int b = 0; b < NB; ++b){
        float acc = mb[t];
        #pragma unroll 4
        for (int k = 0; k < 128; ++k){
            float p = 0.f;
            #pragma unroll
            for (int kb = 0; kb < 16; ++kb) p += pooled16[kb*512 + b*128 + k];
            p = p > 0.f ? p : 0.f;
            acc = fmaf(p, mw[t*128 + k], acc);
        }
        float st = acc > 0.f ? acc : 0.f;
        red[t] = st * cw[t];
        __syncthreads();
        for (int off = 128; off > 0; off >>= 1){
            if (t < off) red[t] += red[t + off];
            __syncthreads();
        }
        if (t == 0) out[b] = red[0] + cb[0];
        __syncthreads();
    }
}

extern "C" void kernel_launch(void* const* d_in, const int* in_sizes, int n_in,
                              void* d_out, int out_size, void* d_ws, size_t ws_size,
                              hipStream_t stream) {
    const float* cov   = (const float*)d_in[0];
    const float* nodes = (const float*)d_in[1];
    const int*   edges = (const int*)d_in[2];
    const int*   c2l   = (const int*)d_in[3];
    const float* ggc   = (const float*)d_in[4];
    const float* wih   = (const float*)d_in[5];
    const float* whh   = (const float*)d_in[6];
    const float* bih   = (const float*)d_in[7];
    const float* bhh   = (const float*)d_in[8];
    const float* aiw   = (const float*)d_in[9];
    const float* aib   = (const float*)d_in[10];
    const float* ajw   = (const float*)d_in[11];
    const float* ajb   = (const float*)d_in[12];
    const float* mlpw  = (const float*)d_in[13];
    const float* mlpb  = (const float*)d_in[14];
    const float* cw    = (const float*)d_in[15];
    const float* cb    = (const float*)d_in[16];
    float* out = (float*)d_out;

    const size_t XSZ = (size_t)BN * 64;          // 12.8M elements
    float* ws = (float*)d_ws;
    float* pooled16 = ws;                        // 16*512 floats
    ushort* xS    = (ushort*)(pooled16 + 8192);  // bf16 interleaved state (in-place)
    ushort* x0I   = xS + XSZ;                    // bf16 interleaved x0
    ushort* aggx  = x0I + XSZ;                   // bf16 agg, interleaved records
    ushort* x0C   = aggx + XSZ;                  // NN*64 batch-invariant x0
    ushort* covB  = x0C + (size_t)NN*64;         // NN*4 per-batch cov
    ushort* whhb  = covB + (size_t)NN*4;         // 12288
    ushort* aiwb  = whhb + 12288;                // 16384
    ushort* ajwb  = aiwb + 16384;                // 16384
    ushort* wfb   = ajwb + 16384;                // 5*12288 fused ih weights
    int* cnt       = (int*)(wfb + 61440);
    int* tmp       = cnt + NN;
    int* bsum      = tmp + NN;
    int* boff      = bsum + 256;
    int* row_start = boff + 256;
    int* cursor    = row_start + (NN + 1);
    int* csr_src   = cursor + NN;

    hipMemsetAsync(cnt, 0, (size_t)NN*sizeof(int), stream);
    hipMemsetAsync(pooled16, 0, 8192*sizeof(float), stream);
    hipMemsetAsync(covB, 0, (size_t)NN*4*sizeof(ushort), stream);

    k_prep<<<416, 256, 0, stream>>>(wih, whh, aiw, ajw, ggc, whhb, aiwb, ajwb, wfb);

    k_hist<<<(NE + 255)/256, 256, 0, stream>>>(edges, cnt);
    k_scan1<<<SCAN_NBLK, 256, 0, stream>>>(cnt, tmp, bsum);
    k_scan2<<<1, 256, 0, stream>>>(bsum, boff);
    k_scan3<<<SCAN_NBLK, 256, 0, stream>>>(tmp, boff, row_start, cursor);
    k_fillcsr<<<(NE + 255)/256, 256, 0, stream>>>(edges, cursor, csr_src);

    k_x0<<<(BN*16)/256, 256, 0, stream>>>(nodes, x0I, x0C);
    k_cov<<<(NB*NL + 255)/256, 256, 0, stream>>>(cov, c2l, x0I, covB);

    for (int i = 0; i < NLAY; ++i){
        const ushort* xin = (i == 0) ? x0I : xS;
        const ushort* wf  = wfb + (size_t)i*12288;
        if (i == 0)
            k_agg0<<<NN/4, 256, 0, stream>>>(x0C, covB, row_start, csr_src, aggx);
        else
            k_agg<<<NN/4, 256, 0, stream>>>(xS, row_start, csr_src, aggx);
        if (i < NLAY - 1)
            k_gruF<<<NTILES, 256, 0, stream>>>(xin, aggx, wf, whhb, bih, bhh, xS);
        else
            k_gruL<<<NTILES, 256, 0, stream>>>(xin, aggx, wf, whhb, bih, bhh,
                                               x0I, aiwb, aib, ajwb, ajb, pooled16);
    }

    k_final<<<1, 256, 0, stream>>>(pooled16, mlpw, mlpb, cw, cb, out);
    (void)in_sizes; (void)n_in; (void)out_size; (void)ws_size;
}

// Round 13
// 662.913 us; speedup vs baseline: 1.6922x; 1.0436x over previous
//
#include <hip/hip_runtime.h>
#include <math.h>

#define NN 50000
#define NF 63
#define NE 800000
#define NL 10000
#define NB 4
#define NLAY 5
#define BN (NB*NN)                 // 200000 rows
#define NTILES (BN/64)             // 3125 blocks (64 rows = 16 nodes each)
#define SCAN_NBLK ((NN+255)/256)   // 196
#define HIST_NBLK ((NE+255)/256)   // 3125

using f32x4  = __attribute__((ext_vector_type(4))) float;
using bf16x8 = __attribute__((ext_vector_type(8))) __bf16;

__device__ __forceinline__ float frcp(float x){ return __builtin_amdgcn_rcpf(x); }
__device__ __forceinline__ float sigm(float v){ return frcp(1.f + __expf(-v)); }
__device__ __forceinline__ float tanh_f(float v){ return fmaf(-2.f, frcp(__expf(2.f*v) + 1.f), 1.f); }

__device__ __forceinline__ ushort f2bf(float f){
    uint u = __builtin_bit_cast(uint, f);
    u += 0x7fffu + ((u >> 16) & 1u);
    return (ushort)(u >> 16);
}
__device__ __forceinline__ float bf_lo(uint v){ return __builtin_bit_cast(float, v << 16); }
__device__ __forceinline__ float bf_hi(uint v){ return __builtin_bit_cast(float, v & 0xffff0000u); }
__device__ __forceinline__ float bfu(ushort v){ return __builtin_bit_cast(float, ((uint)v) << 16); }

__device__ __forceinline__ bf16x8 ldfrag(const ushort* p){
    uint4 v = *(const uint4*)p;
    return __builtin_bit_cast(bf16x8, v);
}
__device__ __forceinline__ f32x4 MFMA(bf16x8 a, bf16x8 b, f32x4 c){
    return __builtin_amdgcn_mfma_f32_16x16x32_bf16(a, b, c, 0, 0, 0);
}

// ---------------- hist + weight prep (merged: independent input-only work) ----------------
__global__ void k_setup(const int* __restrict__ edges, int* __restrict__ cnt,
                        const float* __restrict__ wih, const float* __restrict__ whh,
                        const float* __restrict__ aiw, const float* __restrict__ ajw,
                        const float* __restrict__ ggc,
                        ushort* __restrict__ whhb, ushort* __restrict__ aiwb,
                        ushort* __restrict__ ajwb, ushort* __restrict__ wfb){
    int bid = blockIdx.x;
    if (bid < HIST_NBLK){
        int e = bid*256 + threadIdx.x;
        if (e < NE) atomicAdd(&cnt[edges[NE + e]], 1);
        return;
    }
    int i = (bid - HIST_NBLK)*256 + threadIdx.x;   // 0..106495
    if (i < 12288)        whhb[i]        = f2bf(whh[i]);
    else if (i < 28672)   aiwb[i-12288]  = f2bf(aiw[i-12288]);
    else if (i < 45056)   ajwb[i-28672]  = f2bf(ajw[i-28672]);
    else if (i < 106496){
        int t = i - 45056;                         // 0..61439
        int lay = t / 12288;
        int rem = t % 12288;
        int n = rem >> 6, k = rem & 63;
        const float* W  = ggc + lay*4096 + k*64;
        const float* wr = wih + n*64;
        float s = 0.f;
        #pragma unroll 8
        for (int c = 0; c < 64; ++c) s = fmaf(W[c], wr[c], s);
        wfb[t] = f2bf(s);
    }
}

__global__ void k_scan1(const int* __restrict__ cnt, int* __restrict__ tmp, int* __restrict__ bsum){
    __shared__ int sh[256];
    int tx = threadIdx.x, i = blockIdx.x*256 + tx;
    int v = (i < NN) ? cnt[i] : 0;
    sh[tx] = v; __syncthreads();
    for (int off = 1; off < 256; off <<= 1){
        int u = (tx >= off) ? sh[tx-off] : 0;
        __syncthreads();
        sh[tx] += u;
        __syncthreads();
    }
    int incl = sh[tx];
    if (i < NN) tmp[i] = incl - v;
    if (tx == 255) bsum[blockIdx.x] = incl;
}

__global__ void k_scan2(const int* __restrict__ bsum, int* __restrict__ boff){
    __shared__ int sh[256];
    int tx = threadIdx.x;
    int v = (tx < SCAN_NBLK) ? bsum[tx] : 0;
    sh[tx] = v; __syncthreads();
    for (int off = 1; off < 256; off <<= 1){
        int u = (tx >= off) ? sh[tx-off] : 0;
        __syncthreads();
        sh[tx] += u;
        __syncthreads();
    }
    boff[tx] = sh[tx] - v;
}

__global__ void k_scan3(const int* __restrict__ tmp, const int* __restrict__ boff,
                        int* __restrict__ row_start, int* __restrict__ cursor){
    int i = blockIdx.x*256 + threadIdx.x;
    if (i < NN){
        int rs = tmp[i] + boff[blockIdx.x];
        row_start[i] = rs;
        cursor[i] = rs;
    }
    if (i == 0) row_start[NN] = NE;
}

__global__ void k_fillcsr(const int* __restrict__ edges, int* __restrict__ cursor, int* __restrict__ csr_src){
    int e = blockIdx.x*256 + threadIdx.x;
    if (e < NE){
        int d = edges[NE + e];
        int pos = atomicAdd(&cursor[d], 1);
        csr_src[pos] = edges[e];
    }
}

// ---------------- x0 build: interleaved x0I + batch-invariant x0C ----------------
__global__ void k_x0(const float* __restrict__ nodes, ushort* __restrict__ x0I,
                     ushort* __restrict__ x0C){
    int f = blockIdx.x*256 + threadIdx.x;       // 8B group index, BN*16 total
    int row = f >> 4, c4 = f & 15;
    int n = row % NN, b = row / NN;
    float v[4];
    #pragma unroll
    for (int i = 0; i < 4; ++i){
        int c = c4*4 + i;
        v[i] = (c < NF) ? nodes[(size_t)n*NF + c] : 0.f;
    }
    uint2 pk;
    pk.x = (uint)f2bf(v[0]) | ((uint)f2bf(v[1]) << 16);
    pk.y = (uint)f2bf(v[2]) | ((uint)f2bf(v[3]) << 16);
    *(uint2*)(x0I + ((size_t)n*4 + b)*64 + c4*4) = pk;
    if (b == 0) *(uint2*)(x0C + (size_t)n*64 + c4*4) = pk;   // col63 stays 0
}

__global__ void k_cov(const float* __restrict__ cov, const int* __restrict__ c2l,
                      ushort* __restrict__ x0I, ushort* __restrict__ covB){
    int i = blockIdx.x*256 + threadIdx.x;
    if (i < NB*NL){
        int b = i / NL, j = i % NL;
        int nd = c2l[j];
        ushort vb = f2bf(cov[i]);
        x0I[((size_t)nd*4 + b)*64 + 63] = vb;
        covB[(size_t)nd*4 + b] = vb;
    }
}

// ---------------- layer-0 agg: batch-invariant gather (128B + 8B per edge) ----------------
__global__ __launch_bounds__(256) void k_agg0(const ushort* __restrict__ x0C,
                                              const ushort* __restrict__ covB,
                                              const int* __restrict__ row_start,
                                              const int* __restrict__ csr_src,
                                              ushort* __restrict__ aggx){
    int tx = threadIdx.x, l = tx & 63, w = tx >> 6;
    int d = __builtin_amdgcn_readfirstlane(blockIdx.x*4 + w);
    int h = l >> 5, t = l & 31;                 // half-wave per edge; lane t covers cols 2t,2t+1
    int e0 = row_start[d], e1 = row_start[d+1];
    float a0 = 0.f, a1 = 0.f, c = 0.f;
    int e = e0 + h;
    for (; e + 6 < e1; e += 8){
        int s0 = csr_src[e], s1 = csr_src[e+2], s2 = csr_src[e+4], s3 = csr_src[e+6];
        uint v0 = *(const uint*)(x0C + (size_t)s0*64 + t*2);
        uint v1 = *(const uint*)(x0C + (size_t)s1*64 + t*2);
        uint v2 = *(const uint*)(x0C + (size_t)s2*64 + t*2);
        uint v3 = *(const uint*)(x0C + (size_t)s3*64 + t*2);
        a0 += bf_lo(v0)+bf_lo(v1)+bf_lo(v2)+bf_lo(v3);
        a1 += bf_hi(v0)+bf_hi(v1)+bf_hi(v2)+bf_hi(v3);
        if (t < 4){
            c += bf_lo((uint)covB[(size_t)s0*4 + t]) + bf_lo((uint)covB[(size_t)s1*4 + t])
               + bf_lo((uint)covB[(size_t)s2*4 + t]) + bf_lo((uint)covB[(size_t)s3*4 + t]);
        }
    }
    for (; e < e1; e += 2){
        int s0 = csr_src[e];
        uint v0 = *(const uint*)(x0C + (size_t)s0*64 + t*2);
        a0 += bf_lo(v0); a1 += bf_hi(v0);
        if (t < 4) c += bf_lo((uint)covB[(size_t)s0*4 + t]);
    }
    a0 += __shfl_xor(a0, 32);
    a1 += __shfl_xor(a1, 32);
    c  += __shfl_xor(c, 32);
    float cb0 = __shfl(c, 0), cb1 = __shfl(c, 1), cb2 = __shfl(c, 2), cb3 = __shfl(c, 3);
    if (h == 0){
        uint pk = (uint)f2bf(a0) | ((uint)f2bf(a1) << 16);
        float cb[4] = {cb0, cb1, cb2, cb3};
        #pragma unroll
        for (int b = 0; b < 4; ++b){
            uint o = pk;
            if (t == 31) o = (o & 0xffffu) | ((uint)f2bf(cb[b]) << 16);
            *(uint*)(aggx + (size_t)d*256 + b*64 + t*2) = o;   // interleaved record
        }
    }
}

// ---------------- generic agg: half-wave per edge, uint4 loads, 16 edges in flight ----------------
__global__ __launch_bounds__(256) void k_agg(const ushort* __restrict__ xI,
                                             const int* __restrict__ row_start,
                                             const int* __restrict__ csr_src,
                                             ushort* __restrict__ aggx){
    int tx = threadIdx.x, l = tx & 63, w = tx >> 6;
    int d = __builtin_amdgcn_readfirstlane(blockIdx.x*4 + w);
    int h = l >> 5;                     // half-wave: even/odd edges
    int t = l & 31;                     // 16B group within the 512B record
    const uint off = (uint)(t*8);       // ushort offset
    int e0 = row_start[d], e1 = row_start[d+1];
    float a0=0.f,a1=0.f,a2=0.f,a3=0.f,a4=0.f,a5=0.f,a6=0.f,a7=0.f;
    int e = e0 + h;
    for (; e + 14 < e1; e += 16){       // 8 loads in flight per half-wave = 16 edges/wave
        int s[8];
        #pragma unroll
        for (int j = 0; j < 8; ++j) s[j] = csr_src[e + 2*j];
        uint4 v[8];
        #pragma unroll
        for (int j = 0; j < 8; ++j) v[j] = *(const uint4*)(xI + (size_t)s[j]*256 + off);
        #pragma unroll
        for (int j = 0; j < 8; ++j){
            a0 += bf_lo(v[j].x); a1 += bf_hi(v[j].x);
            a2 += bf_lo(v[j].y); a3 += bf_hi(v[j].y);
            a4 += bf_lo(v[j].z); a5 += bf_hi(v[j].z);
            a6 += bf_lo(v[j].w); a7 += bf_hi(v[j].w);
        }
    }
    for (; e + 6 < e1; e += 8){
        int s[4];
        #pragma unroll
        for (int j = 0; j < 4; ++j) s[j] = csr_src[e + 2*j];
        uint4 v[4];
        #pragma unroll
        for (int j = 0; j < 4; ++j) v[j] = *(const uint4*)(xI + (size_t)s[j]*256 + off);
        #pragma unroll
        for (int j = 0; j < 4; ++j){
            a0 += bf_lo(v[j].x); a1 += bf_hi(v[j].x);
            a2 += bf_lo(v[j].y); a3 += bf_hi(v[j].y);
            a4 += bf_lo(v[j].z); a5 += bf_hi(v[j].z);
            a6 += bf_lo(v[j].w); a7 += bf_hi(v[j].w);
        }
    }
    for (; e < e1; e += 2){
        int s0 = csr_src[e];
        uint4 v0 = *(const uint4*)(xI + (size_t)s0*256 + off);
        a0 += bf_lo(v0.x); a1 += bf_hi(v0.x);
        a2 += bf_lo(v0.y); a3 += bf_hi(v0.y);
        a4 += bf_lo(v0.z); a5 += bf_hi(v0.z);
        a6 += bf_lo(v0.w); a7 += bf_hi(v0.w);
    }
    a0 += __shfl_xor(a0, 32); a1 += __shfl_xor(a1, 32);
    a2 += __shfl_xor(a2, 32); a3 += __shfl_xor(a3, 32);
    a4 += __shfl_xor(a4, 32); a5 += __shfl_xor(a5, 32);
    a6 += __shfl_xor(a6, 32); a7 += __shfl_xor(a7, 32);
    if (h == 0){
        uint4 o;
        o.x = (uint)f2bf(a0) | ((uint)f2bf(a1) << 16);
        o.y = (uint)f2bf(a2) | ((uint)f2bf(a3) << 16);
        o.z = (uint)f2bf(a4) | ((uint)f2bf(a5) << 16);
        o.w = (uint)f2bf(a6) | ((uint)f2bf(a7) << 16);
        *(uint4*)(aggx + (size_t)d*256 + off) = o;   // 32 lanes x 16B = full record
    }
}

// ---------------- shared GRU core: staged LDS tiles -> xnew ----------------
__device__ __forceinline__ void gru_core(const ushort* sAgg, const ushort* sX,
                                         const ushort* __restrict__ wfb, const ushort* __restrict__ whhb,
                                         const float* __restrict__ bih, const float* __restrict__ bhh,
                                         int li, int q, int n0, ushort xn[4][4]){
    f32x4 Cr[4], Cz[4], Cxn[4], Chn[4];
    #pragma unroll
    for (int m = 0; m < 4; ++m){
        Cr[m]=(f32x4){0.f,0.f,0.f,0.f}; Cz[m]=(f32x4){0.f,0.f,0.f,0.f};
        Cxn[m]=(f32x4){0.f,0.f,0.f,0.f}; Chn[m]=(f32x4){0.f,0.f,0.f,0.f};
    }
    #pragma unroll
    for (int ks = 0; ks < 4; ++ks){
        const ushort* wb = (ks < 2) ? wfb : whhb;
        const ushort* sT = (ks < 2) ? sAgg : sX;
        const int kb = (ks & 1)*32;
        bf16x8 Br = ldfrag(wb + (size_t)(n0 + li)*64 + kb + q*8);
        bf16x8 Bz = ldfrag(wb + (size_t)(64 + n0 + li)*64 + kb + q*8);
        bf16x8 Bn = ldfrag(wb + (size_t)(128 + n0 + li)*64 + kb + q*8);
        #pragma unroll
        for (int m = 0; m < 4; ++m){
            bf16x8 A = ldfrag(&sT[(m*16 + li)*72 + kb + q*8]);
            Cr[m] = MFMA(A, Br, Cr[m]);
            Cz[m] = MFMA(A, Bz, Cz[m]);
            if (ks < 2) Cxn[m] = MFMA(A, Bn, Cxn[m]);
            else        Chn[m] = MFMA(A, Bn, Chn[m]);
        }
    }
    const int c = n0 + li;
    const float br_ = bih[c]     + bhh[c];
    const float bz_ = bih[64+c]  + bhh[64+c];
    const float bn_ = bih[128+c];
    const float bh_ = bhh[128+c];
    #pragma unroll
    for (int m = 0; m < 4; ++m){
        #pragma unroll
        for (int rg = 0; rg < 4; ++rg){
            int rl = m*16 + q*4 + rg;
            float r = sigm(Cr[m][rg] + br_);
            float z = sigm(Cz[m][rg] + bz_);
            float nng = tanh_f(Cxn[m][rg] + bn_ + r*(Chn[m][rg] + bh_));
            float v = (1.f - z)*nng + z*bfu(sX[rl*72 + c]);
            xn[m][rg] = f2bf(v);
        }
    }
}

// ---------------- GRU layer (non-last): staged, 1 barrier, in-place ----------------
__global__ __launch_bounds__(256) void k_gruF(const ushort* __restrict__ xsrc,
                                              const ushort* __restrict__ aggx,
                                              const ushort* __restrict__ wfb, const ushort* __restrict__ whhb,
                                              const float* __restrict__ bih, const float* __restrict__ bhh,
                                              ushort* __restrict__ xout){
    __shared__ __align__(16) ushort sAgg[64*72];
    __shared__ __align__(16) ushort sX[64*72];
    const int tx = threadIdx.x;
    const int l  = tx & 63, li = l & 15, q = l >> 4;
    const int w  = __builtin_amdgcn_readfirstlane(tx >> 6);
    const int R0 = blockIdx.x*64;

    #pragma unroll
    for (int it = 0; it < 2; ++it){
        int idx = it*256 + tx, r = idx >> 3, g = idx & 7;
        size_t go = (size_t)(R0 + r)*64 + g*8;
        *(uint4*)(&sAgg[r*72 + g*8]) = *(const uint4*)(aggx + go);
        *(uint4*)(&sX[r*72 + g*8])   = *(const uint4*)(xsrc + go);
    }
    __syncthreads();

    ushort xn[4][4];
    gru_core(sAgg, sX, wfb, whhb, bih, bhh, li, q, 16*w, xn);

    const int c = 16*w + li;
    #pragma unroll
    for (int m = 0; m < 4; ++m)
        #pragma unroll
        for (int rg = 0; rg < 4; ++rg)
            xout[(size_t)(R0 + m*16 + q*4 + rg)*64 + c] = xn[m][rg];
}

// ---------------- GRU layer (last): + fused attention ----------------
__global__ __launch_bounds__(256) void k_gruL(const ushort* __restrict__ xsrc,
                                              const ushort* __restrict__ aggx,
                                              const ushort* __restrict__ wfb, const ushort* __restrict__ whhb,
                                              const float* __restrict__ bih, const float* __restrict__ bhh,
                                              const ushort* __restrict__ x0I,
                                              const ushort* __restrict__ aiwb, const float* __restrict__ aib,
                                              const ushort* __restrict__ ajwb, const float* __restrict__ ajb,
                                              float* __restrict__ pooled16){
    __shared__ __align__(16) ushort sAgg[64*72];
    __shared__ __align__(16) ushort sX[64*72];
    const int tx = threadIdx.x;
    const int l  = tx & 63, li = l & 15, q = l >> 4;
    const int w  = __builtin_amdgcn_readfirstlane(tx >> 6);
    const int R0 = blockIdx.x*64;

    #pragma unroll
    for (int it = 0; it < 2; ++it){
        int idx = it*256 + tx, r = idx >> 3, g = idx & 7;
        size_t go = (size_t)(R0 + r)*64 + g*8;
        *(uint4*)(&sAgg[r*72 + g*8]) = *(const uint4*)(aggx + go);
        *(uint4*)(&sX[r*72 + g*8])   = *(const uint4*)(xsrc + go);
    }
    __syncthreads();

    ushort xn[4][4];
    gru_core(sAgg, sX, wfb, whhb, bih, bhh, li, q, 16*w, xn);
    __syncthreads();                              // all reads of sAgg/sX done

    // cat tile: x' -> sAgg (transpose from C-layout), x0 -> sX (coalesced)
    const int c = 16*w + li;
    #pragma unroll
    for (int m = 0; m < 4; ++m)
        #pragma unroll
        for (int rg = 0; rg < 4; ++rg)
            sAgg[(m*16 + q*4 + rg)*72 + c] = xn[m][rg];
    #pragma unroll
    for (int it = 0; it < 2; ++it){
        int idx = it*256 + tx, r = idx >> 3, g = idx & 7;
        *(uint4*)(&sX[r*72 + g*8]) = *(const uint4*)(x0I + (size_t)(R0 + r)*64 + g*8);
    }
    __syncthreads();

    f32x4 Ai[2][4], Aj[2][4];
    #pragma unroll
    for (int t = 0; t < 2; ++t)
        #pragma unroll
        for (int m = 0; m < 4; ++m){ Ai[t][m]=(f32x4){0.f,0.f,0.f,0.f}; Aj[t][m]=(f32x4){0.f,0.f,0.f,0.f}; }

    const int nb0 = 32*w;
    #pragma unroll
    for (int ks = 0; ks < 4; ++ks){
        const ushort* sT = (ks < 2) ? sAgg : sX;
        const int kb = (ks & 1)*32;
        bf16x8 Bi[2], Bj[2];
        #pragma unroll
        for (int t = 0; t < 2; ++t){
            Bi[t] = ldfrag(aiwb + (size_t)(nb0 + 16*t + li)*128 + ks*32 + q*8);
            Bj[t] = ldfrag(ajwb + (size_t)(nb0 + 16*t + li)*128 + ks*32 + q*8);
        }
        #pragma unroll
        for (int m = 0; m < 4; ++m){
            bf16x8 A = ldfrag(&sT[(m*16 + li)*72 + kb + q*8]);
            #pragma unroll
            for (int t = 0; t < 2; ++t){
                Ai[t][m] = MFMA(A, Bi[t], Ai[t][m]);
                Aj[t][m] = MFMA(A, Bj[t], Aj[t][m]);
            }
        }
    }

    float* pb = pooled16 + (size_t)(blockIdx.x & 15)*512;
    #pragma unroll
    for (int t = 0; t < 2; ++t){
        int cc = nb0 + 16*t + li;
        float bia = aib[cc], bja = ajb[cc];
        float vs[4] = {0.f, 0.f, 0.f, 0.f};
        #pragma unroll
        for (int m = 0; m < 4; ++m){
            #pragma unroll
            for (int rg = 0; rg < 4; ++rg){
                float s = sigm(Ai[t][m][rg] + bia);
                float a = Aj[t][m][rg] + bja;
                a = a > 0.f ? a : 0.f;
                vs[rg] += s*a;                    // batch == rg (interleaved rows)
            }
        }
        #pragma unroll
        for (int b = 0; b < 4; ++b){
            vs[b] += __shfl_xor(vs[b], 16);
            vs[b] += __shfl_xor(vs[b], 32);
        }
        if (l < 16){
            #pragma unroll
            for (int b = 0; b < 4; ++b) atomicAdd(&pb[b*128 + nb0 + 16*t + l], vs[b]);
        }
    }
}

// ---------------- final MLP + critic: one block per batch ----------------
__global__ void k_final(const float* __restrict__ pooled16, const float* __restrict__ mw,
                        const float* __restrict__ mb, const float* __restrict__ cw,
                        const float* __restrict__ cb, float* __restrict__ out){
    __shared__ float red[256];
    int t = threadIdx.x;
    int b = blockIdx.x;
    float acc = mb[t];
    #pragma unroll 4
    for (int k = 0; k < 128; ++k){
        float p = 0.f;
        #pragma unroll
        for (int kb = 0; kb < 16; ++kb) p += pooled16[kb*512 + b*128 + k];
        p = p > 0.f ? p : 0.f;
        acc = fmaf(p, mw[t*128 + k], acc);
    }
    float st = acc > 0.f ? acc : 0.f;
    red[t] = st * cw[t];
    __syncthreads();
    for (int off = 128; off > 0; off >>= 1){
        if (t < off) red[t] += red[t + off];
        __syncthreads();
    }
    if (t == 0) out[b] = red[0] + cb[0];
}

extern "C" void kernel_launch(void* const* d_in, const int* in_sizes, int n_in,
                              void* d_out, int out_size, void* d_ws, size_t ws_size,
                              hipStream_t stream) {
    const float* cov   = (const float*)d_in[0];
    const float* nodes = (const float*)d_in[1];
    const int*   edges = (const int*)d_in[2];
    const int*   c2l   = (const int*)d_in[3];
    const float* ggc   = (const float*)d_in[4];
    const float* wih   = (const float*)d_in[5];
    const float* whh   = (const float*)d_in[6];
    const float* bih   = (const float*)d_in[7];
    const float* bhh   = (const float*)d_in[8];
    const float* aiw   = (const float*)d_in[9];
    const float* aib   = (const float*)d_in[10];
    const float* ajw   = (const float*)d_in[11];
    const float* ajb   = (const float*)d_in[12];
    const float* mlpw  = (const float*)d_in[13];
    const float* mlpb  = (const float*)d_in[14];
    const float* cw    = (const float*)d_in[15];
    const float* cb    = (const float*)d_in[16];
    float* out = (float*)d_out;

    const size_t XSZ = (size_t)BN * 64;          // 12.8M elements
    float* ws = (float*)d_ws;
    float* pooled16 = ws;                        // 16*512 floats
    ushort* xS    = (ushort*)(pooled16 + 8192);  // bf16 interleaved state (in-place)
    ushort* x0I   = xS + XSZ;                    // bf16 interleaved x0
    ushort* aggx  = x0I + XSZ;                   // bf16 agg, interleaved records
    ushort* x0C   = aggx + XSZ;                  // NN*64 batch-invariant x0
    ushort* covB  = x0C + (size_t)NN*64;         // NN*4 per-batch cov
    ushort* whhb  = covB + (size_t)NN*4;         // 12288
    ushort* aiwb  = whhb + 12288;                // 16384
    ushort* ajwb  = aiwb + 16384;                // 16384
    ushort* wfb   = ajwb + 16384;                // 5*12288 fused ih weights
    int* cnt       = (int*)(wfb + 61440);
    int* tmp       = cnt + NN;
    int* bsum      = tmp + NN;
    int* boff      = bsum + 256;
    int* row_start = boff + 256;
    int* cursor    = row_start + (NN + 1);
    int* csr_src   = cursor + NN;

    hipMemsetAsync(cnt, 0, (size_t)NN*sizeof(int), stream);
    hipMemsetAsync(pooled16, 0, 8192*sizeof(float), stream);
    hipMemsetAsync(covB, 0, (size_t)NN*4*sizeof(ushort), stream);

    k_setup<<<HIST_NBLK + 416, 256, 0, stream>>>(edges, cnt, wih, whh, aiw, ajw, ggc,
                                                 whhb, aiwb, ajwb, wfb);
    k_scan1<<<SCAN_NBLK, 256, 0, stream>>>(cnt, tmp, bsum);
    k_scan2<<<1, 256, 0, stream>>>(bsum, boff);
    k_scan3<<<SCAN_NBLK, 256, 0, stream>>>(tmp, boff, row_start, cursor);
    k_fillcsr<<<(NE + 255)/256, 256, 0, stream>>>(edges, cursor, csr_src);

    k_x0<<<(BN*16)/256, 256, 0, stream>>>(nodes, x0I, x0C);
    k_cov<<<(NB*NL + 255)/256, 256, 0, stream>>>(cov, c2l, x0I, covB);

    for (int i = 0; i < NLAY; ++i){
        const ushort* xin = (i == 0) ? x0I : xS;
        const ushort* wf  = wfb + (size_t)i*12288;
        if (i == 0)
            k_agg0<<<NN/4, 256, 0, stream>>>(x0C, covB, row_start, csr_src, aggx);
        else
            k_agg<<<NN/4, 256, 0, stream>>>(xS, row_start, csr_src, aggx);
        if (i < NLAY - 1)
            k_gruF<<<NTILES, 256, 0, stream>>>(xin, aggx, wf, whhb, bih, bhh, xS);
        else
            k_gruL<<<NTILES, 256, 0, stream>>>(xin, aggx, wf, whhb, bih, bhh,
                                               x0I, aiwb, aib, ajwb, ajb, pooled16);
    }

    k_final<<<NB, 256, 0, stream>>>(pooled16, mlpw, mlpb, cw, cb, out);
    (void)in_sizes; (void)n_in; (void)out_size; (void)ws_size;
}

// Round 14
// 617.664 us; speedup vs baseline: 1.8161x; 1.0733x over previous
//
#include <hip/hip_runtime.h>
#include <math.h>

#define NN 50000
#define NF 63
#define NE 800000
#define NL 10000
#define NB 4
#define NLAY 5
#define BN (NB*NN)                 // 200000 rows
#define NTILES (BN/64)             // 3125 blocks (64 rows = 16 nodes each)
#define SCAN_NBLK ((NN+255)/256)   // 196
#define HIST_NBLK ((NE+255)/256)   // 3125

using f32x4  = __attribute__((ext_vector_type(4))) float;
using f32x2  = __attribute__((ext_vector_type(2))) float;
using bf16x8 = __attribute__((ext_vector_type(8))) __bf16;

__device__ __forceinline__ float frcp(float x){ return __builtin_amdgcn_rcpf(x); }
__device__ __forceinline__ float sigm(float v){ return frcp(1.f + __expf(-v)); }
__device__ __forceinline__ float tanh_f(float v){ return fmaf(-2.f, frcp(__expf(2.f*v) + 1.f), 1.f); }

__device__ __forceinline__ ushort f2bf(float f){
    uint u = __builtin_bit_cast(uint, f);
    u += 0x7fffu + ((u >> 16) & 1u);
    return (ushort)(u >> 16);
}
__device__ __forceinline__ float bf_lo(uint v){ return __builtin_bit_cast(float, v << 16); }
__device__ __forceinline__ float bf_hi(uint v){ return __builtin_bit_cast(float, v & 0xffff0000u); }
__device__ __forceinline__ float bfu(ushort v){ return __builtin_bit_cast(float, ((uint)v) << 16); }

__device__ __forceinline__ uchar f2fp8(float v){
    int enc = __builtin_amdgcn_cvt_pk_fp8_f32(v, v, 0, false);
    return (uchar)(enc & 0xff);
}

__device__ __forceinline__ bf16x8 ldfrag(const ushort* p){
    uint4 v = *(const uint4*)p;
    return __builtin_bit_cast(bf16x8, v);
}
__device__ __forceinline__ f32x4 MFMA(bf16x8 a, bf16x8 b, f32x4 c){
    return __builtin_amdgcn_mfma_f32_16x16x32_bf16(a, b, c, 0, 0, 0);
}

// ---------------- hist + weight prep (merged) ----------------
__global__ void k_setup(const int* __restrict__ edges, int* __restrict__ cnt,
                        const float* __restrict__ wih, const float* __restrict__ whh,
                        const float* __restrict__ aiw, const float* __restrict__ ajw,
                        const float* __restrict__ ggc,
                        ushort* __restrict__ whhb, ushort* __restrict__ aiwb,
                        ushort* __restrict__ ajwb, ushort* __restrict__ wfb){
    int bid = blockIdx.x;
    if (bid < HIST_NBLK){
        int e = bid*256 + threadIdx.x;
        if (e < NE) atomicAdd(&cnt[edges[NE + e]], 1);
        return;
    }
    int i = (bid - HIST_NBLK)*256 + threadIdx.x;   // 0..106495
    if (i < 12288)        whhb[i]        = f2bf(whh[i]);
    else if (i < 28672)   aiwb[i-12288]  = f2bf(aiw[i-12288]);
    else if (i < 45056)   ajwb[i-28672]  = f2bf(ajw[i-28672]);
    else if (i < 106496){
        int t = i - 45056;                         // 0..61439
        int lay = t / 12288;
        int rem = t % 12288;
        int n = rem >> 6, k = rem & 63;
        const float* W  = ggc + lay*4096 + k*64;
        const float* wr = wih + n*64;
        float s = 0.f;
        #pragma unroll 8
        for (int c = 0; c < 64; ++c) s = fmaf(W[c], wr[c], s);
        wfb[t] = f2bf(s);
    }
}

__global__ void k_scan1(const int* __restrict__ cnt, int* __restrict__ tmp, int* __restrict__ bsum){
    __shared__ int sh[256];
    int tx = threadIdx.x, i = blockIdx.x*256 + tx;
    int v = (i < NN) ? cnt[i] : 0;
    sh[tx] = v; __syncthreads();
    for (int off = 1; off < 256; off <<= 1){
        int u = (tx >= off) ? sh[tx-off] : 0;
        __syncthreads();
        sh[tx] += u;
        __syncthreads();
    }
    int incl = sh[tx];
    if (i < NN) tmp[i] = incl - v;
    if (tx == 255) bsum[blockIdx.x] = incl;
}

__global__ void k_scan2(const int* __restrict__ bsum, int* __restrict__ boff){
    __shared__ int sh[256];
    int tx = threadIdx.x;
    int v = (tx < SCAN_NBLK) ? bsum[tx] : 0;
    sh[tx] = v; __syncthreads();
    for (int off = 1; off < 256; off <<= 1){
        int u = (tx >= off) ? sh[tx-off] : 0;
        __syncthreads();
        sh[tx] += u;
        __syncthreads();
    }
    boff[tx] = sh[tx] - v;
}

__global__ void k_scan3(const int* __restrict__ tmp, const int* __restrict__ boff,
                        int* __restrict__ row_start, int* __restrict__ cursor){
    int i = blockIdx.x*256 + threadIdx.x;
    if (i < NN){
        int rs = tmp[i] + boff[blockIdx.x];
        row_start[i] = rs;
        cursor[i] = rs;
    }
    if (i == 0) row_start[NN] = NE;
}

__global__ void k_fillcsr(const int* __restrict__ edges, int* __restrict__ cursor, int* __restrict__ csr_src){
    int e = blockIdx.x*256 + threadIdx.x;
    if (e < NE){
        int d = edges[NE + e];
        int pos = atomicAdd(&cursor[d], 1);
        csr_src[pos] = edges[e];
    }
}

// ---------------- x0 build: interleaved x0I + batch-invariant x0C ----------------
__global__ void k_x0(const float* __restrict__ nodes, ushort* __restrict__ x0I,
                     ushort* __restrict__ x0C){
    int f = blockIdx.x*256 + threadIdx.x;       // 8B group index, BN*16 total
    int row = f >> 4, c4 = f & 15;
    int n = row % NN, b = row / NN;
    float v[4];
    #pragma unroll
    for (int i = 0; i < 4; ++i){
        int c = c4*4 + i;
        v[i] = (c < NF) ? nodes[(size_t)n*NF + c] : 0.f;
    }
    uint2 pk;
    pk.x = (uint)f2bf(v[0]) | ((uint)f2bf(v[1]) << 16);
    pk.y = (uint)f2bf(v[2]) | ((uint)f2bf(v[3]) << 16);
    *(uint2*)(x0I + ((size_t)n*4 + b)*64 + c4*4) = pk;
    if (b == 0) *(uint2*)(x0C + (size_t)n*64 + c4*4) = pk;   // col63 stays 0
}

__global__ void k_cov(const float* __restrict__ cov, const int* __restrict__ c2l,
                      ushort* __restrict__ x0I, ushort* __restrict__ covB){
    int i = blockIdx.x*256 + threadIdx.x;
    if (i < NB*NL){
        int b = i / NL, j = i % NL;
        int nd = c2l[j];
        ushort vb = f2bf(cov[i]);
        x0I[((size_t)nd*4 + b)*64 + 63] = vb;
        covB[(size_t)nd*4 + b] = vb;
    }
}

// ---------------- layer-0 agg: batch-invariant gather (bf16, 128B + 8B per edge) ----------------
__global__ __launch_bounds__(256) void k_agg0(const ushort* __restrict__ x0C,
                                              const ushort* __restrict__ covB,
                                              const int* __restrict__ row_start,
                                              const int* __restrict__ csr_src,
                                              ushort* __restrict__ aggx){
    int tx = threadIdx.x, l = tx & 63, w = tx >> 6;
    int d = __builtin_amdgcn_readfirstlane(blockIdx.x*4 + w);
    int h = l >> 5, t = l & 31;                 // half-wave per edge; lane t covers cols 2t,2t+1
    int e0 = row_start[d], e1 = row_start[d+1];
    float a0 = 0.f, a1 = 0.f, c = 0.f;
    int e = e0 + h;
    for (; e + 6 < e1; e += 8){
        int s0 = csr_src[e], s1 = csr_src[e+2], s2 = csr_src[e+4], s3 = csr_src[e+6];
        uint v0 = *(const uint*)(x0C + (size_t)s0*64 + t*2);
        uint v1 = *(const uint*)(x0C + (size_t)s1*64 + t*2);
        uint v2 = *(const uint*)(x0C + (size_t)s2*64 + t*2);
        uint v3 = *(const uint*)(x0C + (size_t)s3*64 + t*2);
        a0 += bf_lo(v0)+bf_lo(v1)+bf_lo(v2)+bf_lo(v3);
        a1 += bf_hi(v0)+bf_hi(v1)+bf_hi(v2)+bf_hi(v3);
        if (t < 4){
            c += bf_lo((uint)covB[(size_t)s0*4 + t]) + bf_lo((uint)covB[(size_t)s1*4 + t])
               + bf_lo((uint)covB[(size_t)s2*4 + t]) + bf_lo((uint)covB[(size_t)s3*4 + t]);
        }
    }
    for (; e < e1; e += 2){
        int s0 = csr_src[e];
        uint v0 = *(const uint*)(x0C + (size_t)s0*64 + t*2);
        a0 += bf_lo(v0); a1 += bf_hi(v0);
        if (t < 4) c += bf_lo((uint)covB[(size_t)s0*4 + t]);
    }
    a0 += __shfl_xor(a0, 32);
    a1 += __shfl_xor(a1, 32);
    c  += __shfl_xor(c, 32);
    float cb0 = __shfl(c, 0), cb1 = __shfl(c, 1), cb2 = __shfl(c, 2), cb3 = __shfl(c, 3);
    if (h == 0){
        uint pk = (uint)f2bf(a0) | ((uint)f2bf(a1) << 16);
        float cb[4] = {cb0, cb1, cb2, cb3};
        #pragma unroll
        for (int b = 0; b < 4; ++b){
            uint o = pk;
            if (t == 31) o = (o & 0xffffu) | ((uint)f2bf(cb[b]) << 16);
            *(uint*)(aggx + (size_t)d*256 + b*64 + t*2) = o;   // interleaved record
        }
    }
}

// ---------------- generic agg: fp8 records (256B), 16 edges in flight ----------------
__global__ __launch_bounds__(256) void k_agg(const uchar* __restrict__ xF,
                                             const int* __restrict__ row_start,
                                             const int* __restrict__ csr_src,
                                             ushort* __restrict__ aggx){
    int tx = threadIdx.x, l = tx & 63, w = tx >> 6;
    int d = __builtin_amdgcn_readfirstlane(blockIdx.x*4 + w);
    int h = l >> 5;                     // half-wave: even/odd edges
    int t = l & 31;                     // 8B group within the 256B fp8 record
    const uint off = (uint)(t*8);       // byte offset
    int e0 = row_start[d], e1 = row_start[d+1];
    float a0=0.f,a1=0.f,a2=0.f,a3=0.f,a4=0.f,a5=0.f,a6=0.f,a7=0.f;
    int e = e0 + h;
    for (; e + 14 < e1; e += 16){       // 8 loads in flight per half-wave = 16 edges/wave
        int s[8];
        #pragma unroll
        for (int j = 0; j < 8; ++j) s[j] = csr_src[e + 2*j];
        uint2 v[8];
        #pragma unroll
        for (int j = 0; j < 8; ++j) v[j] = *(const uint2*)(xF + (size_t)s[j]*256 + off);
        #pragma unroll
        for (int j = 0; j < 8; ++j){
            f32x2 p;
            p = __builtin_amdgcn_cvt_pk_f32_fp8(v[j].x, false); a0 += p.x; a1 += p.y;
            p = __builtin_amdgcn_cvt_pk_f32_fp8(v[j].x, true);  a2 += p.x; a3 += p.y;
            p = __builtin_amdgcn_cvt_pk_f32_fp8(v[j].y, false); a4 += p.x; a5 += p.y;
            p = __builtin_amdgcn_cvt_pk_f32_fp8(v[j].y, true);  a6 += p.x; a7 += p.y;
        }
    }
    for (; e + 6 < e1; e += 8){
        int s[4];
        #pragma unroll
        for (int j = 0; j < 4; ++j) s[j] = csr_src[e + 2*j];
        uint2 v[4];
        #pragma unroll
        for (int j = 0; j < 4; ++j) v[j] = *(const uint2*)(xF + (size_t)s[j]*256 + off);
        #pragma unroll
        for (int j = 0; j < 4; ++j){
            f32x2 p;
            p = __builtin_amdgcn_cvt_pk_f32_fp8(v[j].x, false); a0 += p.x; a1 += p.y;
            p = __builtin_amdgcn_cvt_pk_f32_fp8(v[j].x, true);  a2 += p.x; a3 += p.y;
            p = __builtin_amdgcn_cvt_pk_f32_fp8(v[j].y, false); a4 += p.x; a5 += p.y;
            p = __builtin_amdgcn_cvt_pk_f32_fp8(v[j].y, true);  a6 += p.x; a7 += p.y;
        }
    }
    for (; e < e1; e += 2){
        int s0 = csr_src[e];
        uint2 v0 = *(const uint2*)(xF + (size_t)s0*256 + off);
        f32x2 p;
        p = __builtin_amdgcn_cvt_pk_f32_fp8(v0.x, false); a0 += p.x; a1 += p.y;
        p = __builtin_amdgcn_cvt_pk_f32_fp8(v0.x, true);  a2 += p.x; a3 += p.y;
        p = __builtin_amdgcn_cvt_pk_f32_fp8(v0.y, false); a4 += p.x; a5 += p.y;
        p = __builtin_amdgcn_cvt_pk_f32_fp8(v0.y, true);  a6 += p.x; a7 += p.y;
    }
    a0 += __shfl_xor(a0, 32); a1 += __shfl_xor(a1, 32);
    a2 += __shfl_xor(a2, 32); a3 += __shfl_xor(a3, 32);
    a4 += __shfl_xor(a4, 32); a5 += __shfl_xor(a5, 32);
    a6 += __shfl_xor(a6, 32); a7 += __shfl_xor(a7, 32);
    if (h == 0){
        uint4 o;
        o.x = (uint)f2bf(a0) | ((uint)f2bf(a1) << 16);
        o.y = (uint)f2bf(a2) | ((uint)f2bf(a3) << 16);
        o.z = (uint)f2bf(a4) | ((uint)f2bf(a5) << 16);
        o.w = (uint)f2bf(a6) | ((uint)f2bf(a7) << 16);
        *(uint4*)(aggx + (size_t)d*256 + off) = o;   // bf16 agg, full record
    }
}

// ---------------- shared GRU core: staged LDS tiles -> x' (float) ----------------
__device__ __forceinline__ void gru_core(const ushort* sAgg, const ushort* sX,
                                         const ushort* __restrict__ wfb, const ushort* __restrict__ whhb,
                                         const float* __restrict__ bih, const float* __restrict__ bhh,
                                         int li, int q, int n0, float xv[4][4]){
    f32x4 Cr[4], Cz[4], Cxn[4], Chn[4];
    #pragma unroll
    for (int m = 0; m < 4; ++m){
        Cr[m]=(f32x4){0.f,0.f,0.f,0.f}; Cz[m]=(f32x4){0.f,0.f,0.f,0.f};
        Cxn[m]=(f32x4){0.f,0.f,0.f,0.f}; Chn[m]=(f32x4){0.f,0.f,0.f,0.f};
    }
    #pragma unroll
    for (int ks = 0; ks < 4; ++ks){
        const ushort* wb = (ks < 2) ? wfb : whhb;
        const ushort* sT = (ks < 2) ? sAgg : sX;
        const int kb = (ks & 1)*32;
        bf16x8 Br = ldfrag(wb + (size_t)(n0 + li)*64 + kb + q*8);
        bf16x8 Bz = ldfrag(wb + (size_t)(64 + n0 + li)*64 + kb + q*8);
        bf16x8 Bn = ldfrag(wb + (size_t)(128 + n0 + li)*64 + kb + q*8);
        #pragma unroll
        for (int m = 0; m < 4; ++m){
            bf16x8 A = ldfrag(&sT[(m*16 + li)*72 + kb + q*8]);
            Cr[m] = MFMA(A, Br, Cr[m]);
            Cz[m] = MFMA(A, Bz, Cz[m]);
            if (ks < 2) Cxn[m] = MFMA(A, Bn, Cxn[m]);
            else        Chn[m] = MFMA(A, Bn, Chn[m]);
        }
    }
    const int c = n0 + li;
    const float br_ = bih[c]     + bhh[c];
    const float bz_ = bih[64+c]  + bhh[64+c];
    const float bn_ = bih[128+c];
    const float bh_ = bhh[128+c];
    #pragma unroll
    for (int m = 0; m < 4; ++m){
        #pragma unroll
        for (int rg = 0; rg < 4; ++rg){
            int rl = m*16 + q*4 + rg;
            float r = sigm(Cr[m][rg] + br_);
            float z = sigm(Cz[m][rg] + bz_);
            float nng = tanh_f(Cxn[m][rg] + bn_ + r*(Chn[m][rg] + bh_));
            xv[m][rg] = (1.f - z)*nng + z*bfu(sX[rl*72 + c]);
        }
    }
}

// ---------------- GRU layer (non-last): bf16 state + fp8 gather copy ----------------
__global__ __launch_bounds__(256) void k_gruF(const ushort* __restrict__ xsrc,
                                              const ushort* __restrict__ aggx,
                                              const ushort* __restrict__ wfb, const ushort* __restrict__ whhb,
                                              const float* __restrict__ bih, const float* __restrict__ bhh,
                                              ushort* __restrict__ xout, uchar* __restrict__ xFout){
    __shared__ __align__(16) ushort sAgg[64*72];
    __shared__ __align__(16) ushort sX[64*72];
    const int tx = threadIdx.x;
    const int l  = tx & 63, li = l & 15, q = l >> 4;
    const int w  = __builtin_amdgcn_readfirstlane(tx >> 6);
    const int R0 = blockIdx.x*64;

    #pragma unroll
    for (int it = 0; it < 2; ++it){
        int idx = it*256 + tx, r = idx >> 3, g = idx & 7;
        size_t go = (size_t)(R0 + r)*64 + g*8;
        *(uint4*)(&sAgg[r*72 + g*8]) = *(const uint4*)(aggx + go);
        *(uint4*)(&sX[r*72 + g*8])   = *(const uint4*)(xsrc + go);
    }
    __syncthreads();

    float xv[4][4];
    gru_core(sAgg, sX, wfb, whhb, bih, bhh, li, q, 16*w, xv);

    const int c = 16*w + li;
    #pragma unroll
    for (int m = 0; m < 4; ++m)
        #pragma unroll
        for (int rg = 0; rg < 4; ++rg){
            size_t ro = (size_t)(R0 + m*16 + q*4 + rg)*64 + c;
            xout[ro]  = f2bf(xv[m][rg]);
            xFout[ro] = f2fp8(xv[m][rg]);
        }
}

// ---------------- GRU layer (last): + fused attention ----------------
__global__ __launch_bounds__(256) void k_gruL(const ushort* __restrict__ xsrc,
                                              const ushort* __restrict__ aggx,
                                              const ushort* __restrict__ wfb, const ushort* __restrict__ whhb,
                                              const float* __restrict__ bih, const float* __restrict__ bhh,
                                              const ushort* __restrict__ x0I,
                                              const ushort* __restrict__ aiwb, const float* __restrict__ aib,
                                              const ushort* __restrict__ ajwb, const float* __restrict__ ajb,
                                              float* __restrict__ pooled16){
    __shared__ __align__(16) ushort sAgg[64*72];
    __shared__ __align__(16) ushort sX[64*72];
    const int tx = threadIdx.x;
    const int l  = tx & 63, li = l & 15, q = l >> 4;
    const int w  = __builtin_amdgcn_readfirstlane(tx >> 6);
    const int R0 = blockIdx.x*64;

    #pragma unroll
    for (int it = 0; it < 2; ++it){
        int idx = it*256 + tx, r = idx >> 3, g = idx & 7;
        size_t go = (size_t)(R0 + r)*64 + g*8;
        *(uint4*)(&sAgg[r*72 + g*8]) = *(const uint4*)(aggx + go);
        *(uint4*)(&sX[r*72 + g*8])   = *(const uint4*)(xsrc + go);
    }
    __syncthreads();

    float xv[4][4];
    gru_core(sAgg, sX, wfb, whhb, bih, bhh, li, q, 16*w, xv);
    __syncthreads();                              // all reads of sAgg/sX done

    // cat tile: x' -> sAgg (transpose from C-layout), x0 -> sX (coalesced)
    const int c = 16*w + li;
    #pragma unroll
    for (int m = 0; m < 4; ++m)
        #pragma unroll
        for (int rg = 0; rg < 4; ++rg)
            sAgg[(m*16 + q*4 + rg)*72 + c] = f2bf(xv[m][rg]);
    #pragma unroll
    for (int it = 0; it < 2; ++it){
        int idx = it*256 + tx, r = idx >> 3, g = idx & 7;
        *(uint4*)(&sX[r*72 + g*8]) = *(const uint4*)(x0I + (size_t)(R0 + r)*64 + g*8);
    }
    __syncthreads();

    f32x4 Ai[2][4], Aj[2][4];
    #pragma unroll
    for (int t = 0; t < 2; ++t)
        #pragma unroll
        for (int m = 0; m < 4; ++m){ Ai[t][m]=(f32x4){0.f,0.f,0.f,0.f}; Aj[t][m]=(f32x4){0.f,0.f,0.f,0.f}; }

    const int nb0 = 32*w;
    #pragma unroll
    for (int ks = 0; ks < 4; ++ks){
        const ushort* sT = (ks < 2) ? sAgg : sX;
        const int kb = (ks & 1)*32;
        bf16x8 Bi[2], Bj[2];
        #pragma unroll
        for (int t = 0; t < 2; ++t){
            Bi[t] = ldfrag(aiwb + (size_t)(nb0 + 16*t + li)*128 + ks*32 + q*8);
            Bj[t] = ldfrag(ajwb + (size_t)(nb0 + 16*t + li)*128 + ks*32 + q*8);
        }
        #pragma unroll
        for (int m = 0; m < 4; ++m){
            bf16x8 A = ldfrag(&sT[(m*16 + li)*72 + kb + q*8]);
            #pragma unroll
            for (int t = 0; t < 2; ++t){
                Ai[t][m] = MFMA(A, Bi[t], Ai[t][m]);
                Aj[t][m] = MFMA(A, Bj[t], Aj[t][m]);
            }
        }
    }

    float* pb = pooled16 + (size_t)(blockIdx.x & 15)*512;
    #pragma unroll
    for (int t = 0; t < 2; ++t){
        int cc = nb0 + 16*t + li;
        float bia = aib[cc], bja = ajb[cc];
        float vs[4] = {0.f, 0.f, 0.f, 0.f};
        #pragma unroll
        for (int m = 0; m < 4; ++m){
            #pragma unroll
            for (int rg = 0; rg < 4; ++rg){
                float s = sigm(Ai[t][m][rg] + bia);
                float a = Aj[t][m][rg] + bja;
                a = a > 0.f ? a : 0.f;
                vs[rg] += s*a;                    // batch == rg (interleaved rows)
            }
        }
        #pragma unroll
        for (int b = 0; b < 4; ++b){
            vs[b] += __shfl_xor(vs[b], 16);
            vs[b] += __shfl_xor(vs[b], 32);
        }
        if (l < 16){
            #pragma unroll
            for (int b = 0; b < 4; ++b) atomicAdd(&pb[b*128 + nb0 + 16*t + l], vs[b]);
        }
    }
}

// ---------------- final MLP + critic: one block per batch ----------------
__global__ void k_final(const float* __restrict__ pooled16, const float* __restrict__ mw,
                        const float* __restrict__ mb, const float* __restrict__ cw,
                        const float* __restrict__ cb, float* __restrict__ out){
    __shared__ float red[256];
    int t = threadIdx.x;
    int b = blockIdx.x;
    float acc = mb[t];
    #pragma unroll 4
    for (int k = 0; k < 128; ++k){
        float p = 0.f;
        #pragma unroll
        for (int kb = 0; kb < 16; ++kb) p += pooled16[kb*512 + b*128 + k];
        p = p > 0.f ? p : 0.f;
        acc = fmaf(p, mw[t*128 + k], acc);
    }
    float st = acc > 0.f ? acc : 0.f;
    red[t] = st * cw[t];
    __syncthreads();
    for (int off = 128; off > 0; off >>= 1){
        if (t < off) red[t] += red[t + off];
        __syncthreads();
    }
    if (t == 0) out[b] = red[0] + cb[0];
}

extern "C" void kernel_launch(void* const* d_in, const int* in_sizes, int n_in,
                              void* d_out, int out_size, void* d_ws, size_t ws_size,
                              hipStream_t stream) {
    const float* cov   = (const float*)d_in[0];
    const float* nodes = (const float*)d_in[1];
    const int*   edges = (const int*)d_in[2];
    const int*   c2l   = (const int*)d_in[3];
    const float* ggc   = (const float*)d_in[4];
    const float* wih   = (const float*)d_in[5];
    const float* whh   = (const float*)d_in[6];
    const float* bih   = (const float*)d_in[7];
    const float* bhh   = (const float*)d_in[8];
    const float* aiw   = (const float*)d_in[9];
    const float* aib   = (const float*)d_in[10];
    const float* ajw   = (const float*)d_in[11];
    const float* ajb   = (const float*)d_in[12];
    const float* mlpw  = (const float*)d_in[13];
    const float* mlpb  = (const float*)d_in[14];
    const float* cw    = (const float*)d_in[15];
    const float* cb    = (const float*)d_in[16];
    float* out = (float*)d_out;

    const size_t XSZ = (size_t)BN * 64;          // 12.8M elements
    float* ws = (float*)d_ws;
    float* pooled16 = ws;                        // 16*512 floats
    ushort* xS    = (ushort*)(pooled16 + 8192);  // bf16 interleaved state (in-place)
    ushort* x0I   = xS + XSZ;                    // bf16 interleaved x0
    ushort* aggx  = x0I + XSZ;                   // bf16 agg, interleaved records
    ushort* x0C   = aggx + XSZ;                  // NN*64 batch-invariant x0
    ushort* covB  = x0C + (size_t)NN*64;         // NN*4 per-batch cov
    ushort* whhb  = covB + (size_t)NN*4;         // 12288
    ushort* aiwb  = whhb + 12288;                // 16384
    ushort* ajwb  = aiwb + 16384;                // 16384
    ushort* wfb   = ajwb + 16384;                // 5*12288 fused ih weights
    uchar* xF     = (uchar*)(wfb + 61440);       // fp8 interleaved state, BN*64 bytes
    int* cnt       = (int*)(xF + XSZ);
    int* tmp       = cnt + NN;
    int* bsum      = tmp + NN;
    int* boff      = bsum + 256;
    int* row_start = boff + 256;
    int* cursor    = row_start + (NN + 1);
    int* csr_src   = cursor + NN;

    hipMemsetAsync(cnt, 0, (size_t)NN*sizeof(int), stream);
    hipMemsetAsync(pooled16, 0, 8192*sizeof(float), stream);
    hipMemsetAsync(covB, 0, (size_t)NN*4*sizeof(ushort), stream);

    k_setup<<<HIST_NBLK + 416, 256, 0, stream>>>(edges, cnt, wih, whh, aiw, ajw, ggc,
                                                 whhb, aiwb, ajwb, wfb);
    k_scan1<<<SCAN_NBLK, 256, 0, stream>>>(cnt, tmp, bsum);
    k_scan2<<<1, 256, 0, stream>>>(bsum, boff);
    k_scan3<<<SCAN_NBLK, 256, 0, stream>>>(tmp, boff, row_start, cursor);
    k_fillcsr<<<(NE + 255)/256, 256, 0, stream>>>(edges, cursor, csr_src);

    k_x0<<<(BN*16)/256, 256, 0, stream>>>(nodes, x0I, x0C);
    k_cov<<<(NB*NL + 255)/256, 256, 0, stream>>>(cov, c2l, x0I, covB);

    for (int i = 0; i < NLAY; ++i){
        const ushort* xin = (i == 0) ? x0I : xS;
        const ushort* wf  = wfb + (size_t)i*12288;
        if (i == 0)
            k_agg0<<<NN/4, 256, 0, stream>>>(x0C, covB, row_start, csr_src, aggx);
        else
            k_agg<<<NN/4, 256, 0, stream>>>(xF, row_start, csr_src, aggx);
        if (i < NLAY - 1)
            k_gruF<<<NTILES, 256, 0, stream>>>(xin, aggx, wf, whhb, bih, bhh, xS, xF);
        else
            k_gruL<<<NTILES, 256, 0, stream>>>(xin, aggx, wf, whhb, bih, bhh,
                                               x0I, aiwb, aib, ajwb, ajb, pooled16);
    }

    k_final<<<NB, 256, 0, stream>>>(pooled16, mlpw, mlpb, cw, cb, out);
    (void)in_sizes; (void)n_in; (void)out_size; (void)ws_size;
}

// Round 15
// 611.577 us; speedup vs baseline: 1.8342x; 1.0100x over previous
//
#include <hip/hip_runtime.h>
#include <math.h>

#define NN 50000
#define NF 63
#define NE 800000
#define NL 10000
#define NB 4
#define NLAY 5
#define BN (NB*NN)                 // 200000 rows
#define NTILES (BN/64)             // 3125 blocks (64 rows = 16 nodes each)
#define SCAN_NBLK ((NN+255)/256)   // 196
#define HIST_NBLK ((NE+255)/256)   // 3125

using f32x4  = __attribute__((ext_vector_type(4))) float;
using f32x2  = __attribute__((ext_vector_type(2))) float;
using bf16x8 = __attribute__((ext_vector_type(8))) __bf16;

__device__ __forceinline__ float frcp(float x){ return __builtin_amdgcn_rcpf(x); }
__device__ __forceinline__ float sigm(float v){ return frcp(1.f + __expf(-v)); }
__device__ __forceinline__ float tanh_f(float v){ return fmaf(-2.f, frcp(__expf(2.f*v) + 1.f), 1.f); }

__device__ __forceinline__ ushort f2bf(float f){
    uint u = __builtin_bit_cast(uint, f);
    u += 0x7fffu + ((u >> 16) & 1u);
    return (ushort)(u >> 16);
}
__device__ __forceinline__ float bf_lo(uint v){ return __builtin_bit_cast(float, v << 16); }
__device__ __forceinline__ float bf_hi(uint v){ return __builtin_bit_cast(float, v & 0xffff0000u); }
__device__ __forceinline__ float bfu(ushort v){ return __builtin_bit_cast(float, ((uint)v) << 16); }

__device__ __forceinline__ uchar f2fp8(float v){
    int enc = __builtin_amdgcn_cvt_pk_fp8_f32(v, v, 0, false);
    return (uchar)(enc & 0xff);
}

__device__ __forceinline__ bf16x8 ldfrag(const ushort* p){
    uint4 v = *(const uint4*)p;
    return __builtin_bit_cast(bf16x8, v);
}
__device__ __forceinline__ f32x4 MFMA(bf16x8 a, bf16x8 b, f32x4 c){
    return __builtin_amdgcn_mfma_f32_16x16x32_bf16(a, b, c, 0, 0, 0);
}

// ---------------- hist + weight prep (merged) ----------------
__global__ void k_setup(const int* __restrict__ edges, int* __restrict__ cnt,
                        const float* __restrict__ wih, const float* __restrict__ whh,
                        const float* __restrict__ aiw, const float* __restrict__ ajw,
                        const float* __restrict__ ggc,
                        ushort* __restrict__ whhb, ushort* __restrict__ aiwb,
                        ushort* __restrict__ ajwb, ushort* __restrict__ wfb){
    int bid = blockIdx.x;
    if (bid < HIST_NBLK){
        int e = bid*256 + threadIdx.x;
        if (e < NE) atomicAdd(&cnt[edges[NE + e]], 1);
        return;
    }
    int i = (bid - HIST_NBLK)*256 + threadIdx.x;   // 0..106495
    if (i < 12288)        whhb[i]        = f2bf(whh[i]);
    else if (i < 28672)   aiwb[i-12288]  = f2bf(aiw[i-12288]);
    else if (i < 45056)   ajwb[i-28672]  = f2bf(ajw[i-28672]);
    else if (i < 106496){
        int t = i - 45056;                         // 0..61439
        int lay = t / 12288;
        int rem = t % 12288;
        int n = rem >> 6, k = rem & 63;
        const float* W  = ggc + lay*4096 + k*64;
        const float* wr = wih + n*64;
        float s = 0.f;
        #pragma unroll 8
        for (int c = 0; c < 64; ++c) s = fmaf(W[c], wr[c], s);
        wfb[t] = f2bf(s);
    }
}

__global__ void k_scan1(const int* __restrict__ cnt, int* __restrict__ tmp, int* __restrict__ bsum){
    __shared__ int sh[256];
    int tx = threadIdx.x, i = blockIdx.x*256 + tx;
    int v = (i < NN) ? cnt[i] : 0;
    sh[tx] = v; __syncthreads();
    for (int off = 1; off < 256; off <<= 1){
        int u = (tx >= off) ? sh[tx-off] : 0;
        __syncthreads();
        sh[tx] += u;
        __syncthreads();
    }
    int incl = sh[tx];
    if (i < NN) tmp[i] = incl - v;
    if (tx == 255) bsum[blockIdx.x] = incl;
}

__global__ void k_scan2(const int* __restrict__ bsum, int* __restrict__ boff){
    __shared__ int sh[256];
    int tx = threadIdx.x;
    int v = (tx < SCAN_NBLK) ? bsum[tx] : 0;
    sh[tx] = v; __syncthreads();
    for (int off = 1; off < 256; off <<= 1){
        int u = (tx >= off) ? sh[tx-off] : 0;
        __syncthreads();
        sh[tx] += u;
        __syncthreads();
    }
    boff[tx] = sh[tx] - v;
}

__global__ void k_scan3(const int* __restrict__ tmp, const int* __restrict__ boff,
                        int* __restrict__ row_start, int* __restrict__ cursor){
    int i = blockIdx.x*256 + threadIdx.x;
    if (i < NN){
        int rs = tmp[i] + boff[blockIdx.x];
        row_start[i] = rs;
        cursor[i] = rs;
    }
    if (i == 0) row_start[NN] = NE;
}

__global__ void k_fillcsr(const int* __restrict__ edges, int* __restrict__ cursor, int* __restrict__ csr_src){
    int e = blockIdx.x*256 + threadIdx.x;
    if (e < NE){
        int d = edges[NE + e];
        int pos = atomicAdd(&cursor[d], 1);
        csr_src[pos] = edges[e];
    }
}

// ---------------- x0 build: interleaved x0I (bf16) + batch-invariant x0F (fp8) ----------------
__global__ void k_x0(const float* __restrict__ nodes, ushort* __restrict__ x0I,
                     uchar* __restrict__ x0F){
    int f = blockIdx.x*256 + threadIdx.x;       // 8B group index, BN*16 total
    int row = f >> 4, c4 = f & 15;
    int n = row % NN, b = row / NN;
    float v[4];
    #pragma unroll
    for (int i = 0; i < 4; ++i){
        int c = c4*4 + i;
        v[i] = (c < NF) ? nodes[(size_t)n*NF + c] : 0.f;
    }
    uint2 pk;
    pk.x = (uint)f2bf(v[0]) | ((uint)f2bf(v[1]) << 16);
    pk.y = (uint)f2bf(v[2]) | ((uint)f2bf(v[3]) << 16);
    *(uint2*)(x0I + ((size_t)n*4 + b)*64 + c4*4) = pk;
    if (b == 0){
        uint q = 0;
        q = (uint)__builtin_amdgcn_cvt_pk_fp8_f32(v[0], v[1], (int)q, false);
        q = (uint)__builtin_amdgcn_cvt_pk_fp8_f32(v[2], v[3], (int)q, true);
        *(uint*)(x0F + (size_t)n*64 + c4*4) = q;   // col63 stays 0 (v[3]=0 at c4=15)
    }
}

__global__ void k_cov(const float* __restrict__ cov, const int* __restrict__ c2l,
                      ushort* __restrict__ x0I, ushort* __restrict__ covB){
    int i = blockIdx.x*256 + threadIdx.x;
    if (i < NB*NL){
        int b = i / NL, j = i % NL;
        int nd = c2l[j];
        ushort vb = f2bf(cov[i]);
        x0I[((size_t)nd*4 + b)*64 + 63] = vb;
        covB[(size_t)nd*4 + b] = vb;
    }
}

// ---------------- layer-0 agg: batch-invariant fp8 gather (64B + 8B per edge) ----------------
// quarter-wave per edge: 16 lanes x uint (4 fp8 cols) = 64B record; 4 edges/step, unroll 4
__global__ __launch_bounds__(256) void k_agg0(const uchar* __restrict__ x0F,
                                              const ushort* __restrict__ covB,
                                              const int* __restrict__ row_start,
                                              const int* __restrict__ csr_src,
                                              ushort* __restrict__ aggx){
    int tx = threadIdx.x, l = tx & 63, w = tx >> 6;
    int d = __builtin_amdgcn_readfirstlane(blockIdx.x*4 + w);
    int h = l >> 4;                             // subgroup 0..3 (edge offset)
    int t = l & 15;                             // uint lane: cols 4t..4t+3
    const uint off = (uint)(t*4);               // byte offset in 64B record
    int e0 = row_start[d], e1 = row_start[d+1];
    float a0=0.f,a1=0.f,a2=0.f,a3=0.f,c=0.f;
    int e = e0 + h;
    for (; e + 12 < e1; e += 16){               // 16 edges in flight across wave
        int s[4];
        #pragma unroll
        for (int j = 0; j < 4; ++j) s[j] = csr_src[e + 4*j];
        uint v[4];
        #pragma unroll
        for (int j = 0; j < 4; ++j) v[j] = *(const uint*)(x0F + (size_t)s[j]*64 + off);
        #pragma unroll
        for (int j = 0; j < 4; ++j){
            f32x2 p;
            p = __builtin_amdgcn_cvt_pk_f32_fp8(v[j], false); a0 += p.x; a1 += p.y;
            p = __builtin_amdgcn_cvt_pk_f32_fp8(v[j], true);  a2 += p.x; a3 += p.y;
        }
        if (t < 4){
            #pragma unroll
            for (int j = 0; j < 4; ++j) c += bf_lo((uint)covB[(size_t)s[j]*4 + t]);
        }
    }
    for (; e < e1; e += 4){
        int s0 = csr_src[e];
        uint v0 = *(const uint*)(x0F + (size_t)s0*64 + off);
        f32x2 p;
        p = __builtin_amdgcn_cvt_pk_f32_fp8(v0, false); a0 += p.x; a1 += p.y;
        p = __builtin_amdgcn_cvt_pk_f32_fp8(v0, true);  a2 += p.x; a3 += p.y;
        if (t < 4) c += bf_lo((uint)covB[(size_t)s0*4 + t]);
    }
    a0 += __shfl_xor(a0, 16); a0 += __shfl_xor(a0, 32);
    a1 += __shfl_xor(a1, 16); a1 += __shfl_xor(a1, 32);
    a2 += __shfl_xor(a2, 16); a2 += __shfl_xor(a2, 32);
    a3 += __shfl_xor(a3, 16); a3 += __shfl_xor(a3, 32);
    c  += __shfl_xor(c, 16);  c  += __shfl_xor(c, 32);
    float cb0 = __shfl(c, 0), cb1 = __shfl(c, 1), cb2 = __shfl(c, 2), cb3 = __shfl(c, 3);
    if (h == 0){
        uint2 pk;
        pk.x = (uint)f2bf(a0) | ((uint)f2bf(a1) << 16);
        pk.y = (uint)f2bf(a2) | ((uint)f2bf(a3) << 16);
        float cb[4] = {cb0, cb1, cb2, cb3};
        #pragma unroll
        for (int b = 0; b < 4; ++b){
            uint2 o = pk;
            if (t == 15) o.y = (o.y & 0xffffu) | ((uint)f2bf(cb[b]) << 16);  // col63 = cov agg
            *(uint2*)(aggx + (size_t)d*256 + b*64 + t*4) = o;
        }
    }
}

// ---------------- generic agg: fp8 records (256B), 16 edges in flight ----------------
__global__ __launch_bounds__(256) void k_agg(const uchar* __restrict__ xF,
                                             const int* __restrict__ row_start,
                                             const int* __restrict__ csr_src,
                                             ushort* __restrict__ aggx){
    int tx = threadIdx.x, l = tx & 63, w = tx >> 6;
    int d = __builtin_amdgcn_readfirstlane(blockIdx.x*4 + w);
    int h = l >> 5;                     // half-wave: even/odd edges
    int t = l & 31;                     // 8B group within the 256B fp8 record
    const uint off = (uint)(t*8);       // byte offset
    int e0 = row_start[d], e1 = row_start[d+1];
    float a0=0.f,a1=0.f,a2=0.f,a3=0.f,a4=0.f,a5=0.f,a6=0.f,a7=0.f;
    int e = e0 + h;
    for (; e + 14 < e1; e += 16){       // 8 loads in flight per half-wave = 16 edges/wave
        int s[8];
        #pragma unroll
        for (int j = 0; j < 8; ++j) s[j] = csr_src[e + 2*j];
        uint2 v[8];
        #pragma unroll
        for (int j = 0; j < 8; ++j) v[j] = *(const uint2*)(xF + (size_t)s[j]*256 + off);
        #pragma unroll
        for (int j = 0; j < 8; ++j){
            f32x2 p;
            p = __builtin_amdgcn_cvt_pk_f32_fp8(v[j].x, false); a0 += p.x; a1 += p.y;
            p = __builtin_amdgcn_cvt_pk_f32_fp8(v[j].x, true);  a2 += p.x; a3 += p.y;
            p = __builtin_amdgcn_cvt_pk_f32_fp8(v[j].y, false); a4 += p.x; a5 += p.y;
            p = __builtin_amdgcn_cvt_pk_f32_fp8(v[j].y, true);  a6 += p.x; a7 += p.y;
        }
    }
    for (; e + 6 < e1; e += 8){
        int s[4];
        #pragma unroll
        for (int j = 0; j < 4; ++j) s[j] = csr_src[e + 2*j];
        uint2 v[4];
        #pragma unroll
        for (int j = 0; j < 4; ++j) v[j] = *(const uint2*)(xF + (size_t)s[j]*256 + off);
        #pragma unroll
        for (int j = 0; j < 4; ++j){
            f32x2 p;
            p = __builtin_amdgcn_cvt_pk_f32_fp8(v[j].x, false); a0 += p.x; a1 += p.y;
            p = __builtin_amdgcn_cvt_pk_f32_fp8(v[j].x, true);  a2 += p.x; a3 += p.y;
            p = __builtin_amdgcn_cvt_pk_f32_fp8(v[j].y, false); a4 += p.x; a5 += p.y;
            p = __builtin_amdgcn_cvt_pk_f32_fp8(v[j].y, true);  a6 += p.x; a7 += p.y;
        }
    }
    for (; e < e1; e += 2){
        int s0 = csr_src[e];
        uint2 v0 = *(const uint2*)(xF + (size_t)s0*256 + off);
        f32x2 p;
        p = __builtin_amdgcn_cvt_pk_f32_fp8(v0.x, false); a0 += p.x; a1 += p.y;
        p = __builtin_amdgcn_cvt_pk_f32_fp8(v0.x, true);  a2 += p.x; a3 += p.y;
        p = __builtin_amdgcn_cvt_pk_f32_fp8(v0.y, false); a4 += p.x; a5 += p.y;
        p = __builtin_amdgcn_cvt_pk_f32_fp8(v0.y, true);  a6 += p.x; a7 += p.y;
    }
    a0 += __shfl_xor(a0, 32); a1 += __shfl_xor(a1, 32);
    a2 += __shfl_xor(a2, 32); a3 += __shfl_xor(a3, 32);
    a4 += __shfl_xor(a4, 32); a5 += __shfl_xor(a5, 32);
    a6 += __shfl_xor(a6, 32); a7 += __shfl_xor(a7, 32);
    if (h == 0){
        uint4 o;
        o.x = (uint)f2bf(a0) | ((uint)f2bf(a1) << 16);
        o.y = (uint)f2bf(a2) | ((uint)f2bf(a3) << 16);
        o.z = (uint)f2bf(a4) | ((uint)f2bf(a5) << 16);
        o.w = (uint)f2bf(a6) | ((uint)f2bf(a7) << 16);
        *(uint4*)(aggx + (size_t)d*256 + off) = o;   // bf16 agg, full record
    }
}

// ---------------- shared GRU core: staged LDS tiles -> x' (float) ----------------
__device__ __forceinline__ void gru_core(const ushort* sAgg, const ushort* sX,
                                         const ushort* __restrict__ wfb, const ushort* __restrict__ whhb,
                                         const float* __restrict__ bih, const float* __restrict__ bhh,
                                         int li, int q, int n0, float xv[4][4]){
    f32x4 Cr[4], Cz[4], Cxn[4], Chn[4];
    #pragma unroll
    for (int m = 0; m < 4; ++m){
        Cr[m]=(f32x4){0.f,0.f,0.f,0.f}; Cz[m]=(f32x4){0.f,0.f,0.f,0.f};
        Cxn[m]=(f32x4){0.f,0.f,0.f,0.f}; Chn[m]=(f32x4){0.f,0.f,0.f,0.f};
    }
    #pragma unroll
    for (int ks = 0; ks < 4; ++ks){
        const ushort* wb = (ks < 2) ? wfb : whhb;
        const ushort* sT = (ks < 2) ? sAgg : sX;
        const int kb = (ks & 1)*32;
        bf16x8 Br = ldfrag(wb + (size_t)(n0 + li)*64 + kb + q*8);
        bf16x8 Bz = ldfrag(wb + (size_t)(64 + n0 + li)*64 + kb + q*8);
        bf16x8 Bn = ldfrag(wb + (size_t)(128 + n0 + li)*64 + kb + q*8);
        #pragma unroll
        for (int m = 0; m < 4; ++m){
            bf16x8 A = ldfrag(&sT[(m*16 + li)*72 + kb + q*8]);
            Cr[m] = MFMA(A, Br, Cr[m]);
            Cz[m] = MFMA(A, Bz, Cz[m]);
            if (ks < 2) Cxn[m] = MFMA(A, Bn, Cxn[m]);
            else        Chn[m] = MFMA(A, Bn, Chn[m]);
        }
    }
    const int c = n0 + li;
    const float br_ = bih[c]     + bhh[c];
    const float bz_ = bih[64+c]  + bhh[64+c];
    const float bn_ = bih[128+c];
    const float bh_ = bhh[128+c];
    #pragma unroll
    for (int m = 0; m < 4; ++m){
        #pragma unroll
        for (int rg = 0; rg < 4; ++rg){
            int rl = m*16 + q*4 + rg;
            float r = sigm(Cr[m][rg] + br_);
            float z = sigm(Cz[m][rg] + bz_);
            float nng = tanh_f(Cxn[m][rg] + bn_ + r*(Chn[m][rg] + bh_));
            xv[m][rg] = (1.f - z)*nng + z*bfu(sX[rl*72 + c]);
        }
    }
}

// ---------------- GRU layer (non-last): bf16 state + fp8 gather copy ----------------
__global__ __launch_bounds__(256) void k_gruF(const ushort* __restrict__ xsrc,
                                              const ushort* __restrict__ aggx,
                                              const ushort* __restrict__ wfb, const ushort* __restrict__ whhb,
                                              const float* __restrict__ bih, const float* __restrict__ bhh,
                                              ushort* __restrict__ xout, uchar* __restrict__ xFout){
    __shared__ __align__(16) ushort sAgg[64*72];
    __shared__ __align__(16) ushort sX[64*72];
    const int tx = threadIdx.x;
    const int l  = tx & 63, li = l & 15, q = l >> 4;
    const int w  = __builtin_amdgcn_readfirstlane(tx >> 6);
    const int R0 = blockIdx.x*64;

    #pragma unroll
    for (int it = 0; it < 2; ++it){
        int idx = it*256 + tx, r = idx >> 3, g = idx & 7;
        size_t go = (size_t)(R0 + r)*64 + g*8;
        *(uint4*)(&sAgg[r*72 + g*8]) = *(const uint4*)(aggx + go);
        *(uint4*)(&sX[r*72 + g*8])   = *(const uint4*)(xsrc + go);
    }
    __syncthreads();

    float xv[4][4];
    gru_core(sAgg, sX, wfb, whhb, bih, bhh, li, q, 16*w, xv);

    const int c = 16*w + li;
    #pragma unroll
    for (int m = 0; m < 4; ++m)
        #pragma unroll
        for (int rg = 0; rg < 4; ++rg){
            size_t ro = (size_t)(R0 + m*16 + q*4 + rg)*64 + c;
            xout[ro]  = f2bf(xv[m][rg]);
            xFout[ro] = f2fp8(xv[m][rg]);
        }
}

// ---------------- GRU layer (last): + fused attention ----------------
__global__ __launch_bounds__(256) void k_gruL(const ushort* __restrict__ xsrc,
                                              const ushort* __restrict__ aggx,
                                              const ushort* __restrict__ wfb, const ushort* __restrict__ whhb,
                                              const float* __restrict__ bih, const float* __restrict__ bhh,
                                              const ushort* __restrict__ x0I,
                                              const ushort* __restrict__ aiwb, const float* __restrict__ aib,
                                              const ushort* __restrict__ ajwb, const float* __restrict__ ajb,
                                              float* __restrict__ pooled16){
    __shared__ __align__(16) ushort sAgg[64*72];
    __shared__ __align__(16) ushort sX[64*72];
    const int tx = threadIdx.x;
    const int l  = tx & 63, li = l & 15, q = l >> 4;
    const int w  = __builtin_amdgcn_readfirstlane(tx >> 6);
    const int R0 = blockIdx.x*64;

    #pragma unroll
    for (int it = 0; it < 2; ++it){
        int idx = it*256 + tx, r = idx >> 3, g = idx & 7;
        size_t go = (size_t)(R0 + r)*64 + g*8;
        *(uint4*)(&sAgg[r*72 + g*8]) = *(const uint4*)(aggx + go);
        *(uint4*)(&sX[r*72 + g*8])   = *(const uint4*)(xsrc + go);
    }
    __syncthreads();

    float xv[4][4];
    gru_core(sAgg, sX, wfb, whhb, bih, bhh, li, q, 16*w, xv);
    __syncthreads();                              // all reads of sAgg/sX done

    // cat tile: x' -> sAgg (transpose from C-layout), x0 -> sX (coalesced)
    const int c = 16*w + li;
    #pragma unroll
    for (int m = 0; m < 4; ++m)
        #pragma unroll
        for (int rg = 0; rg < 4; ++rg)
            sAgg[(m*16 + q*4 + rg)*72 + c] = f2bf(xv[m][rg]);
    #pragma unroll
    for (int it = 0; it < 2; ++it){
        int idx = it*256 + tx, r = idx >> 3, g = idx & 7;
        *(uint4*)(&sX[r*72 + g*8]) = *(const uint4*)(x0I + (size_t)(R0 + r)*64 + g*8);
    }
    __syncthreads();

    f32x4 Ai[2][4], Aj[2][4];
    #pragma unroll
    for (int t = 0; t < 2; ++t)
        #pragma unroll
        for (int m = 0; m < 4; ++m){ Ai[t][m]=(f32x4){0.f,0.f,0.f,0.f}; Aj[t][m]=(f32x4){0.f,0.f,0.f,0.f}; }

    const int nb0 = 32*w;
    #pragma unroll
    for (int ks = 0; ks < 4; ++ks){
        const ushort* sT = (ks < 2) ? sAgg : sX;
        const int kb = (ks & 1)*32;
        bf16x8 Bi[2], Bj[2];
        #pragma unroll
        for (int t = 0; t < 2; ++t){
            Bi[t] = ldfrag(aiwb + (size_t)(nb0 + 16*t + li)*128 + ks*32 + q*8);
            Bj[t] = ldfrag(ajwb + (size_t)(nb0 + 16*t + li)*128 + ks*32 + q*8);
        }
        #pragma unroll
        for (int m = 0; m < 4; ++m){
            bf16x8 A = ldfrag(&sT[(m*16 + li)*72 + kb + q*8]);
            #pragma unroll
            for (int t = 0; t < 2; ++t){
                Ai[t][m] = MFMA(A, Bi[t], Ai[t][m]);
                Aj[t][m] = MFMA(A, Bj[t], Aj[t][m]);
            }
        }
    }

    float* pb = pooled16 + (size_t)(blockIdx.x & 15)*512;
    #pragma unroll
    for (int t = 0; t < 2; ++t){
        int cc = nb0 + 16*t + li;
        float bia = aib[cc], bja = ajb[cc];
        float vs[4] = {0.f, 0.f, 0.f, 0.f};
        #pragma unroll
        for (int m = 0; m < 4; ++m){
            #pragma unroll
            for (int rg = 0; rg < 4; ++rg){
                float s = sigm(Ai[t][m][rg] + bia);
                float a = Aj[t][m][rg] + bja;
                a = a > 0.f ? a : 0.f;
                vs[rg] += s*a;                    // batch == rg (interleaved rows)
            }
        }
        #pragma unroll
        for (int b = 0; b < 4; ++b){
            vs[b] += __shfl_xor(vs[b], 16);
            vs[b] += __shfl_xor(vs[b], 32);
        }
        if (l < 16){
            #pragma unroll
            for (int b = 0; b < 4; ++b) atomicAdd(&pb[b*128 + nb0 + 16*t + l], vs[b]);
        }
    }
}

// ---------------- final MLP + critic: one block per batch ----------------
__global__ void k_final(const float* __restrict__ pooled16, const float* __restrict__ mw,
                        const float* __restrict__ mb, const float* __restrict__ cw,
                        const float* __restrict__ cb, float* __restrict__ out){
    __shared__ float red[256];
    int t = threadIdx.x;
    int b = blockIdx.x;
    float acc = mb[t];
    #pragma unroll 4
    for (int k = 0; k < 128; ++k){
        float p = 0.f;
        #pragma unroll
        for (int kb = 0; kb < 16; ++kb) p += pooled16[kb*512 + b*128 + k];
        p = p > 0.f ? p : 0.f;
        acc = fmaf(p, mw[t*128 + k], acc);
    }
    float st = acc > 0.f ? acc : 0.f;
    red[t] = st * cw[t];
    __syncthreads();
    for (int off = 128; off > 0; off >>= 1){
        if (t < off) red[t] += red[t + off];
        __syncthreads();
    }
    if (t == 0) out[b] = red[0] + cb[0];
}

extern "C" void kernel_launch(void* const* d_in, const int* in_sizes, int n_in,
                              void* d_out, int out_size, void* d_ws, size_t ws_size,
                              hipStream_t stream) {
    const float* cov   = (const float*)d_in[0];
    const float* nodes = (const float*)d_in[1];
    const int*   edges = (const int*)d_in[2];
    const int*   c2l   = (const int*)d_in[3];
    const float* ggc   = (const float*)d_in[4];
    const float* wih   = (const float*)d_in[5];
    const float* whh   = (const float*)d_in[6];
    const float* bih   = (const float*)d_in[7];
    const float* bhh   = (const float*)d_in[8];
    const float* aiw   = (const float*)d_in[9];
    const float* aib   = (const float*)d_in[10];
    const float* ajw   = (const float*)d_in[11];
    const float* ajb   = (const float*)d_in[12];
    const float* mlpw  = (const float*)d_in[13];
    const float* mlpb  = (const float*)d_in[14];
    const float* cw    = (const float*)d_in[15];
    const float* cb    = (const float*)d_in[16];
    float* out = (float*)d_out;

    const size_t XSZ = (size_t)BN * 64;          // 12.8M elements
    float* ws = (float*)d_ws;
    float* pooled16 = ws;                        // 16*512 floats
    ushort* xS    = (ushort*)(pooled16 + 8192);  // bf16 interleaved state (in-place)
    ushort* x0I   = xS + XSZ;                    // bf16 interleaved x0
    ushort* aggx  = x0I + XSZ;                   // bf16 agg, interleaved records
    ushort* covB  = aggx + XSZ;                  // NN*4 per-batch cov
    ushort* whhb  = covB + (size_t)NN*4;         // 12288
    ushort* aiwb  = whhb + 12288;                // 16384
    ushort* ajwb  = aiwb + 16384;                // 16384
    ushort* wfb   = ajwb + 16384;                // 5*12288 fused ih weights
    uchar* xF     = (uchar*)(wfb + 61440);       // fp8 interleaved state, BN*64 bytes
    uchar* x0F    = xF + XSZ;                    // fp8 batch-invariant x0, NN*64 bytes
    int* cnt       = (int*)(x0F + (size_t)NN*64);
    int* tmp       = cnt + NN;
    int* bsum      = tmp + NN;
    int* boff      = bsum + 256;
    int* row_start = boff + 256;
    int* cursor    = row_start + (NN + 1);
    int* csr_src   = cursor + NN;

    hipMemsetAsync(cnt, 0, (size_t)NN*sizeof(int), stream);
    hipMemsetAsync(pooled16, 0, 8192*sizeof(float), stream);
    hipMemsetAsync(covB, 0, (size_t)NN*4*sizeof(ushort), stream);

    k_setup<<<HIST_NBLK + 416, 256, 0, stream>>>(edges, cnt, wih, whh, aiw, ajw, ggc,
                                                 whhb, aiwb, ajwb, wfb);
    k_scan1<<<SCAN_NBLK, 256, 0, stream>>>(cnt, tmp, bsum);
    k_scan2<<<1, 256, 0, stream>>>(bsum, boff);
    k_scan3<<<SCAN_NBLK, 256, 0, stream>>>(tmp, boff, row_start, cursor);
    k_fillcsr<<<(NE + 255)/256, 256, 0, stream>>>(edges, cursor, csr_src);

    k_x0<<<(BN*16)/256, 256, 0, stream>>>(nodes, x0I, x0F);
    k_cov<<<(NB*NL + 255)/256, 256, 0, stream>>>(cov, c2l, x0I, covB);

    for (int i = 0; i < NLAY; ++i){
        const ushort* xin = (i == 0) ? x0I : xS;
        const ushort* wf  = wfb + (size_t)i*12288;
        if (i == 0)
            k_agg0<<<NN/4, 256, 0, stream>>>(x0F, covB, row_start, csr_src, aggx);
        else
            k_agg<<<NN/4, 256, 0, stream>>>(xF, row_start, csr_src, aggx);
        if (i < NLAY - 1)
            k_gruF<<<NTILES, 256, 0, stream>>>(xin, aggx, wf, whhb, bih, bhh, xS, xF);
        else
            k_gruL<<<NTILES, 256, 0, stream>>>(xin, aggx, wf, whhb, bih, bhh,
                                               x0I, aiwb, aib, ajwb, ajb, pooled16);
    }

    k_final<<<NB, 256, 0, stream>>>(pooled16, mlpw, mlpb, cw, cb, out);
    (void)in_sizes; (void)n_in; (void)out_size; (void)ws_size;
}